// Round 13
// baseline (591.090 us; speedup 1.0000x reference)
//
#include <hip/hip_runtime.h>
#include <math.h>

#define C_   512
#define C8_  64
#define HH   96
#define WW   96
#define PP   9216            // HH*WW
#define CP   4718592         // C_*PP
#define C8P  589824          // C8_*PP
#define ATTN 1769472         // PP*192

typedef __attribute__((ext_vector_type(4))) float f32x4;
typedef __attribute__((ext_vector_type(8))) __bf16 bf16x8;
typedef __attribute__((ext_vector_type(8))) unsigned short ushort8;
typedef __attribute__((ext_vector_type(4))) unsigned short ushort4v;
typedef __attribute__((ext_vector_type(2))) unsigned short ushort2v;
typedef __attribute__((ext_vector_type(2))) float float2v;

__device__ __forceinline__ float bf2f(unsigned short u) {
    union { unsigned u; float f; } x; x.u = ((unsigned)u) << 16; return x.f;
}
__device__ __forceinline__ unsigned short f2bf(float f) {
    union { float f; unsigned u; } x; x.f = f;
    unsigned r = x.u + 0x7fffu + ((x.u >> 16) & 1u);
    return (unsigned short)(r >> 16);
}
__device__ __forceinline__ void gload16(const void* g, void* l) {
    __builtin_amdgcn_global_load_lds(
        (const __attribute__((address_space(1))) unsigned int*)g,
        (__attribute__((address_space(3))) unsigned int*)l, 16, 0, 0);
}

// ---------------- all 4 weight casts in one dispatch ----------------
__global__ __launch_bounds__(256) void cast_w(
    const float* __restrict__ Wv, const float* __restrict__ Wqv,
    const float* __restrict__ Wq, const float* __restrict__ Wk,
    unsigned short* __restrict__ oV, unsigned short* __restrict__ oQV,
    unsigned short* __restrict__ oQ, unsigned short* __restrict__ oK)
{
    int y = blockIdx.y;
    int n = (y < 2) ? 262144 : 32768;
    const float* s = (y == 0) ? Wv : (y == 1) ? Wqv : (y == 2) ? Wq : Wk;
    unsigned short* d = (y == 0) ? oV : (y == 1) ? oQV : (y == 2) ? oQ : oK;
    int i = (blockIdx.x * 256 + threadIdx.x) * 4;
    if (i < n) {
        float4 v = *(const float4*)(s + i);
        ushort4v o = { f2bf(v.x), f2bf(v.y), f2bf(v.z), f2bf(v.w) };
        *(ushort4v*)(d + i) = o;
    }
}

// ---------------- x fp32 [C][P] -> xT bf16 [P][C], both tensors ----------------
__global__ __launch_bounds__(256) void cast_transpose_cp(
    const float* __restrict__ xq, const float* __restrict__ xe,
    unsigned short* __restrict__ xTq, unsigned short* __restrict__ xTe)
{
    int zz = blockIdx.z;
    int which = zz & 1;
    size_t b = zz >> 1;
    const float* xb = (which ? xe : xq) + b * (size_t)CP;
    unsigned short* xTb = (which ? xTe : xTq) + b * (size_t)CP;
    int p0 = blockIdx.x * 64, c0 = blockIdx.y * 64;

    __shared__ unsigned short T[64][65];
    int t = threadIdx.x;
    int pp = t & 31, cg = t >> 5;
#pragma unroll
    for (int i = 0; i < 8; ++i) {
        int c = cg + 8 * i;
        float2v v = *(const float2v*)(xb + (size_t)(c0 + c) * PP + p0 + pp * 2);
        T[c][pp * 2] = f2bf(v.x);
        T[c][pp * 2 + 1] = f2bf(v.y);
    }
    __syncthreads();
    int cp = t & 31;
#pragma unroll
    for (int i = 0; i < 8; ++i) {
        int e = t + 256 * i;
        int p = e >> 5;
        ushort2v o = { T[cp * 2][p], T[cp * 2 + 1][p] };
        *(ushort2v*)(xTb + (size_t)(p0 + p) * C_ + c0 + cp * 2) = o;
    }
}

// ---------------- MFMA GEMM q & k (BM=64, bf16 out), 4-deep counted pipeline ----------------
// grid (72, 2, g); per-tile VMEM instrs/wave = 3 (1 A + 2 B); BK=32, 16 tiles
__global__ __launch_bounds__(256) void gemm_qk(
    const unsigned short* __restrict__ Wqb, const unsigned short* __restrict__ Wkb,
    const unsigned short* __restrict__ xTq, const unsigned short* __restrict__ xTe,
    const float* __restrict__ bq, const float* __restrict__ bk,
    unsigned short* __restrict__ qout, unsigned short* __restrict__ kout)
{
    int sel = blockIdx.y;
    const unsigned short* A = sel ? Wkb : Wqb;
    const float* bias = sel ? bk : bq;
    int p0 = blockIdx.x * 128;
    size_t b = blockIdx.z;
    const unsigned short* Bb = (sel ? xTe : xTq) + b * (size_t)CP;
    unsigned short* outb = (sel ? kout : qout) + b * (size_t)C8P;

    __shared__ __align__(16) unsigned short Asm[4][64 * 32];
    __shared__ __align__(16) unsigned short Bsm[4][128 * 32];

    int tid = threadIdx.x;
    int lane = tid & 63, wid = tid >> 6;
    int wr = wid >> 1, wc = wid & 1;
    int l15 = lane & 15, l4 = lane >> 4;
    f32x4 acc[2][4] = {};

    // swizzled stage: chunk (row, slot) holds global k-chunk slot ^ ((row>>1)&3)
#define QK_STAGE(KT, BUF)                                                                   \
    {                                                                                       \
        int k0s = (KT) * 32;                                                                \
        int ra = tid >> 2, sa = tid & 3;                                                    \
        int ga = sa ^ ((ra >> 1) & 3);                                                      \
        gload16(A + (size_t)ra * 512 + k0s + ga * 8, Asm[BUF] + tid * 8);                   \
        _Pragma("unroll")                                                                   \
        for (int i = 0; i < 2; ++i) {                                                       \
            int ch = tid + i * 256;                                                         \
            int rb = ch >> 2, sb = ch & 3;                                                  \
            int gb = sb ^ ((rb >> 1) & 3);                                                  \
            gload16(Bb + (size_t)(p0 + rb) * 512 + k0s + gb * 8, Bsm[BUF] + ch * 8);        \
        }                                                                                   \
    }

    QK_STAGE(0, 0);
    QK_STAGE(1, 1);
    QK_STAGE(2, 2);

#pragma unroll
    for (int k = 0; k < 16; ++k) {
        int cur = k & 3;
        if (k < 14)      asm volatile("s_waitcnt vmcnt(6)" ::: "memory");
        else if (k < 15) asm volatile("s_waitcnt vmcnt(3)" ::: "memory");
        else             asm volatile("s_waitcnt vmcnt(0)" ::: "memory");
        __builtin_amdgcn_s_barrier();
        bf16x8 af[2], bfr[4];
#pragma unroll
        for (int m = 0; m < 2; ++m) {
            int row = wr * 32 + m * 16 + l15;
            int sl = l4 ^ ((row >> 1) & 3);
            af[m] = *(const bf16x8*)&Asm[cur][row * 32 + sl * 8];
        }
#pragma unroll
        for (int n = 0; n < 4; ++n) {
            int row = wc * 64 + n * 16 + l15;
            int sl = l4 ^ ((row >> 1) & 3);
            bfr[n] = *(const bf16x8*)&Bsm[cur][row * 32 + sl * 8];
        }
#pragma unroll
        for (int m = 0; m < 2; ++m)
#pragma unroll
            for (int n = 0; n < 4; ++n)
                acc[m][n] = __builtin_amdgcn_mfma_f32_16x16x32_bf16(af[m], bfr[n], acc[m][n], 0, 0, 0);
        asm volatile("" ::: "memory");
        if (k < 13) QK_STAGE(k + 3, (k + 3) & 3);
    }
#undef QK_STAGE

#pragma unroll
    for (int m = 0; m < 2; ++m)
#pragma unroll
        for (int n = 0; n < 4; ++n) {
            int pcol = p0 + wc * 64 + n * 16 + l15;
#pragma unroll
            for (int r = 0; r < 4; ++r) {
                int orow = wr * 32 + m * 16 + l4 * 4 + r;
                outb[(size_t)orow * PP + pcol] = f2bf(acc[m][n][r] + bias[orow]);
            }
        }
}

// ---------------- bf16 96x96 spatial transpose (q,k only) ----------------
__global__ __launch_bounds__(256) void thw_b(
    const unsigned short* __restrict__ in, unsigned short* __restrict__ out)
{
    size_t m = blockIdx.x;
    const unsigned short* im = in + m * (size_t)PP;
    unsigned short* om = out + m * (size_t)PP;
    __shared__ unsigned short T[96][97];
    int t = threadIdx.x;
#pragma unroll
    for (int i = 0; i < 18; ++i) {
        int v = t + 256 * i;
        int r = v / 48, pp = v - r * 48;
        ushort2v u = *(const ushort2v*)(im + r * 96 + pp * 2);
        T[r][pp * 2] = u.x;
        T[r][pp * 2 + 1] = u.y;
    }
    __syncthreads();
#pragma unroll
    for (int i = 0; i < 18; ++i) {
        int v = t + 256 * i;
        int w = v / 48, hh = v - w * 48;
        ushort2v o = { T[hh * 2][w], T[hh * 2 + 1][w] };
        *(ushort2v*)(om + w * 96 + hh * 2) = o;
    }
}

// ---------------- scores + exp + row-partial-sums: grid (96, 2, g) ----------------
__global__ __launch_bounds__(256) void scores_kernel(
    const unsigned short* __restrict__ qT, const unsigned short* __restrict__ kT,
    const unsigned short* __restrict__ q, const unsigned short* __restrict__ k,
    unsigned short* __restrict__ attb, float* __restrict__ rsum0, float* __restrict__ rsum1)
{
    int s = blockIdx.x;
    int ori = blockIdx.y;
    size_t b = blockIdx.z;
    const unsigned short* qs = (ori ? q : qT) + b * (size_t)C8P;
    const unsigned short* ks = (ori ? k : kT) + b * (size_t)C8P;
    unsigned short* ab = attb + b * (size_t)ATTN;
    float* rs = (ori ? rsum1 : rsum0) + b * (size_t)PP;

    __shared__ float Qs[64][97];
    __shared__ float Ks[64][97];
    int t = threadIdx.x;
    for (int v = t; v < 64 * 12; v += 256) {
        int c = v / 12, gg = v - c * 12;
        size_t gi = (size_t)c * PP + (size_t)s * 96 + gg * 8;
        ushort8 uq = *(const ushort8*)(qs + gi);
        ushort8 uk = *(const ushort8*)(ks + gi);
#pragma unroll
        for (int kk = 0; kk < 8; ++kk) {
            Qs[c][gg * 8 + kk] = bf2f(uq[kk]);
            Ks[c][gg * 8 + kk] = bf2f(uk[kk]);
        }
    }
    __syncthreads();
    int tx = t & 15, ty = t >> 4;
    float acc[6][6] = {};
    for (int c = 0; c < 64; ++c) {
        float qf[6], kf[6];
#pragma unroll
        for (int i = 0; i < 6; ++i) { qf[i] = Qs[c][ty + 16 * i]; kf[i] = Ks[c][tx + 16 * i]; }
#pragma unroll
        for (int i = 0; i < 6; ++i)
#pragma unroll
            for (int j = 0; j < 6; ++j) acc[i][j] = fmaf(qf[i], kf[j], acc[i][j]);
    }
#pragma unroll
    for (int i = 0; i < 6; ++i) {
        int m = ty + 16 * i;
        size_t row = ori ? ((size_t)s * 96 + m) : ((size_t)m * 96 + s);
        unsigned short* rowp = ab + row * 192 + (ori ? 96 : 0);
        float part = 0.0f;
#pragma unroll
        for (int j = 0; j < 6; ++j) {
            int jj = tx + 16 * j;
            float e = (!ori && jj == m) ? 0.0f : __expf(acc[i][j] - 20.0f);
            part += e;
            rowp[jj] = f2bf(e);
        }
#pragma unroll
        for (int off = 1; off < 16; off <<= 1) part += __shfl_xor(part, off);
        if (tx == 0) rs[row] = part;
    }
}

// ---------------- MFMA apply on x (staged from xT, XOR-swizzled): yT[p][c] ----------------
// grid (96 s, 4 = path*2+ct, g), 512 thr = 8 waves (2 m x 4 n)
template<int ORI>
__global__ __launch_bounds__(512) void apply_mfma(
    const unsigned short* __restrict__ xT_e, const unsigned short* __restrict__ xT_q,
    unsigned short* __restrict__ yT_e, unsigned short* __restrict__ yT_q,
    const unsigned short* __restrict__ attb,
    const float* __restrict__ rsum0, const float* __restrict__ rsum1)
{
    int s = blockIdx.x;
    int path = blockIdx.y >> 1, ct = blockIdx.y & 1;
    int c0 = ct * 256;
    size_t b = blockIdx.z;
    const unsigned short* X = (path ? xT_q : xT_e) + b * (size_t)CP;
    unsigned short* Y = (path ? yT_q : yT_e) + b * (size_t)CP;
    const unsigned short* ab = attb + b * (size_t)ATTN;
    const float* r0 = rsum0 + b * (size_t)PP;
    const float* r1 = rsum1 + b * (size_t)PP;

    __shared__ __align__(16) unsigned short Att[96][104];
    __shared__ __align__(16) unsigned short Xs[256][104];   // [c][j], col-group XOR-swizzled by (c>>3)&3

    int tid = threadIdx.x;
    for (int v = tid; v < 96 * 12; v += 512) {
        int r = v / 12, gg = v - r * 12;
        size_t base = ORI ? ((size_t)(s * 96 + r) * 192 + 96) : ((size_t)(r * 96 + s) * 192);
        *(ushort8*)&Att[r][gg * 8] = *(const ushort8*)(ab + base + gg * 8);
    }
    for (int v = tid; v < 96 * 32; v += 512) {
        int j = v >> 5, cc = v & 31;
        size_t pj = ORI ? ((size_t)s * 96 + j) : ((size_t)j * 96 + s);
        ushort8 u = *(const ushort8*)(X + pj * C_ + c0 + cc * 8);
        int js = j ^ ((cc & 3) << 3);
#pragma unroll
        for (int e = 0; e < 8; ++e) Xs[cc * 8 + e][js] = u[e];
    }
    __syncthreads();

    int lane = tid & 63, wid = tid >> 6;
    int wm = wid >> 2, wn = wid & 3;
    int l15 = lane & 15, l4 = lane >> 4;
    f32x4 acc[3][4] = {};
#pragma unroll
    for (int k = 0; k < 3; ++k) {
        bf16x8 a[3], xx[4];
#pragma unroll
        for (int mi = 0; mi < 3; ++mi)
            a[mi] = *(const bf16x8*)&Att[wm * 48 + mi * 16 + l15][k * 32 + l4 * 8];
#pragma unroll
        for (int ni = 0; ni < 4; ++ni) {
            int row = wn * 64 + ni * 16 + l15;
            int gsw = (k * 4 + l4) ^ ((row >> 3) & 3);
            xx[ni] = *(const bf16x8*)&Xs[row][gsw * 8];
        }
#pragma unroll
        for (int mi = 0; mi < 3; ++mi)
#pragma unroll
            for (int ni = 0; ni < 4; ++ni)
                acc[mi][ni] = __builtin_amdgcn_mfma_f32_16x16x32_bf16(a[mi], xx[ni], acc[mi][ni], 0, 0, 0);
    }

#pragma unroll
    for (int mi = 0; mi < 3; ++mi) {
#pragma unroll
        for (int r = 0; r < 4; ++r) {
            int mrow = wm * 48 + mi * 16 + l4 * 4 + r;
            size_t p = ORI ? ((size_t)s * 96 + mrow) : ((size_t)mrow * 96 + s);
            float rinv = 0.0f;
            if (ORI) rinv = 1.0f / (r0[p] + r1[p]);
            size_t base = p * C_ + c0;
#pragma unroll
            for (int ni = 0; ni < 4; ++ni) {
                size_t idx = base + wn * 64 + ni * 16 + l15;
                if (ORI == 0) {
                    Y[idx] = f2bf(acc[mi][ni][r]);
                } else {
                    float tot = bf2f(Y[idx]) + acc[mi][ni][r];
                    Y[idx] = f2bf(tot * rinv);
                }
            }
        }
    }
}

// ---------------- final GEMM + fused epilogue: 512 thr, BK=32, 4-deep counted pipeline ----------------
// grid (72, 8, g); y = path*4 + ot; per-tile VMEM instrs/wave = 2
__global__ __launch_bounds__(512) void gemm_out(
    const unsigned short* __restrict__ Wvb, const unsigned short* __restrict__ Wqvb,
    const unsigned short* __restrict__ yT_e, const unsigned short* __restrict__ yT_q,
    const float* __restrict__ bv, const float* __restrict__ bqv,
    const float* __restrict__ xe, const float* __restrict__ xq,
    const float* __restrict__ g1, const float* __restrict__ g2,
    float* __restrict__ o0, float* __restrict__ o1)
{
    int yy = blockIdx.y;
    int path = yy >> 2, ot = yy & 3;
    const unsigned short* A = path ? Wqvb : Wvb;
    const float* bias = path ? bqv : bv;
    int p0 = blockIdx.x * 128;
    int o0r = ot * 128;
    size_t b = blockIdx.z;
    const unsigned short* Bb = (path ? yT_q : yT_e) + b * (size_t)CP;
    const float* xb = (path ? xq : xe) + b * (size_t)CP;
    float* ob = (path ? o1 : o0) + b * (size_t)CP;
    float gam = (path ? g2 : g1)[0];

    __shared__ __align__(16) unsigned short Asm[4][128 * 32];
    __shared__ __align__(16) unsigned short Bsm[4][128 * 32];

    int tid = threadIdx.x;             // 0..511, 8 waves
    int lane = tid & 63, wid = tid >> 6;
    int wr = wid >> 2, wc = wid & 3;   // 2 x 4 wave grid; wave tile 64 rows x 32 cols
    int l15 = lane & 15, l4 = lane >> 4;
    f32x4 acc[4][2] = {};

    // swizzled stage: chunk (row, slot) holds global k-chunk slot ^ ((row>>1)&3); 1 A + 1 B load/thread
#define GO_STAGE(KT, BUF)                                                                   \
    {                                                                                       \
        int k0s = (KT) * 32;                                                                \
        int row = tid >> 2, slot = tid & 3;                                                 \
        int gs = slot ^ ((row >> 1) & 3);                                                   \
        gload16(A + (size_t)(o0r + row) * 512 + k0s + gs * 8, Asm[BUF] + tid * 8);          \
        gload16(Bb + (size_t)(p0 + row) * 512 + k0s + gs * 8, Bsm[BUF] + tid * 8);          \
    }

    GO_STAGE(0, 0);
    GO_STAGE(1, 1);
    GO_STAGE(2, 2);

#pragma unroll
    for (int k = 0; k < 16; ++k) {
        int cur = k & 3;
        if (k < 14)      asm volatile("s_waitcnt vmcnt(4)" ::: "memory");
        else if (k < 15) asm volatile("s_waitcnt vmcnt(2)" ::: "memory");
        else             asm volatile("s_waitcnt vmcnt(0)" ::: "memory");
        __builtin_amdgcn_s_barrier();
        bf16x8 af[4], bfr[2];
#pragma unroll
        for (int m = 0; m < 4; ++m) {
            int row = wr * 64 + m * 16 + l15;
            int sl = l4 ^ ((row >> 1) & 3);
            af[m] = *(const bf16x8*)&Asm[cur][row * 32 + sl * 8];
        }
#pragma unroll
        for (int n = 0; n < 2; ++n) {
            int row = wc * 32 + n * 16 + l15;
            int sl = l4 ^ ((row >> 1) & 3);
            bfr[n] = *(const bf16x8*)&Bsm[cur][row * 32 + sl * 8];
        }
#pragma unroll
        for (int m = 0; m < 4; ++m)
#pragma unroll
            for (int n = 0; n < 2; ++n)
                acc[m][n] = __builtin_amdgcn_mfma_f32_16x16x32_bf16(af[m], bfr[n], acc[m][n], 0, 0, 0);
        asm volatile("" ::: "memory");
        if (k < 13) GO_STAGE(k + 3, (k + 3) & 3);
    }
#undef GO_STAGE

#pragma unroll
    for (int m = 0; m < 4; ++m)
#pragma unroll
        for (int n = 0; n < 2; ++n) {
            int pcol = p0 + wc * 32 + n * 16 + l15;
#pragma unroll
            for (int r = 0; r < 4; ++r) {
                int orow = o0r + wr * 64 + m * 16 + l4 * 4 + r;
                size_t idx = (size_t)orow * PP + pcol;
                float val = acc[m][n][r] + bias[orow];
                ob[idx] = gam * (val + 2.0f) + xb[idx];
            }
        }
}

extern "C" void kernel_launch(void* const* d_in, const int* in_sizes, int n_in,
                              void* d_out, int out_size, void* d_ws, size_t ws_size,
                              hipStream_t stream)
{
    const float* x_ex = (const float*)d_in[0];
    const float* x_q  = (const float*)d_in[1];
    const float* Wq   = (const float*)d_in[2];
    const float* bq   = (const float*)d_in[3];
    const float* Wk   = (const float*)d_in[4];
    const float* bk   = (const float*)d_in[5];
    const float* Wv   = (const float*)d_in[6];
    const float* bv   = (const float*)d_in[7];
    const float* Wqv  = (const float*)d_in[8];
    const float* bqv  = (const float*)d_in[9];
    const float* g1   = (const float*)d_in[10];
    const float* g2   = (const float*)d_in[11];
    float* out0 = (float*)d_out;
    float* out1 = out0 + (size_t)8 * CP;

    unsigned short* hp = (unsigned short*)d_ws;
    unsigned short* Wvb  = hp; hp += 262144;
    unsigned short* Wqvb = hp; hp += 262144;
    unsigned short* Wqb  = hp; hp += 32768;
    unsigned short* Wkb  = hp; hp += 32768;
    size_t head = (size_t)(hp - (unsigned short*)d_ws) * 2;

    size_t perB = 4ull * CP + (size_t)ATTN + 4ull * C8P + 4ull * PP;
    int g = 8;
    while (g > 1 && head + (size_t)g * perB * 2 > ws_size) g >>= 1;

    unsigned short* p = hp;
    unsigned short* xT_e = p; p += (size_t)g * CP;
    unsigned short* xT_q = p; p += (size_t)g * CP;
    unsigned short* yT_e = p; p += (size_t)g * CP;
    unsigned short* yT_q = p; p += (size_t)g * CP;
    unsigned short* attb = p; p += (size_t)g * ATTN;
    unsigned short* qb   = p; p += (size_t)g * C8P;
    unsigned short* kb   = p; p += (size_t)g * C8P;  // adjacent to qb
    unsigned short* qTb  = p; p += (size_t)g * C8P;
    unsigned short* kTb  = p; p += (size_t)g * C8P;  // adjacent to qTb
    float* rsum0 = (float*)p; p += (size_t)g * PP * 2;
    float* rsum1 = (float*)p; p += (size_t)g * PP * 2;

    cast_w<<<dim3(256, 4), 256, 0, stream>>>(Wv, Wqv, Wq, Wk, Wvb, Wqvb, Wqb, Wkb);

    for (int b0 = 0; b0 < 8; b0 += g) {
        const float* xe = x_ex + (size_t)b0 * CP;
        const float* xq = x_q  + (size_t)b0 * CP;
        float* o0 = out0 + (size_t)b0 * CP;
        float* o1 = out1 + (size_t)b0 * CP;

        cast_transpose_cp<<<dim3(144, 8, 2 * g), 256, 0, stream>>>(xq, xe, xT_q, xT_e);
        gemm_qk<<<dim3(72, 2, g), 256, 0, stream>>>(Wqb, Wkb, xT_q, xT_e, bq, bk, qb, kb);
        thw_b<<<dim3(2 * g * 64), 256, 0, stream>>>(qb, qTb);
        scores_kernel<<<dim3(96, 2, g), 256, 0, stream>>>(qTb, kTb, qb, kb, attb, rsum0, rsum1);
        apply_mfma<0><<<dim3(96, 4, g), 512, 0, stream>>>(xT_e, xT_q, yT_e, yT_q, attb, rsum0, rsum1);
        apply_mfma<1><<<dim3(96, 4, g), 512, 0, stream>>>(xT_e, xT_q, yT_e, yT_q, attb, rsum0, rsum1);
        gemm_out<<<dim3(72, 8, g), 512, 0, stream>>>(Wvb, Wqvb, yT_e, yT_q, bv, bqv,
                                                     xe, xq, g1, g2, o0, o1);
    }
}

// Round 14
// 561.407 us; speedup vs baseline: 1.0529x; 1.0529x over previous
//
#include <hip/hip_runtime.h>
#include <math.h>

#define C_   512
#define C8_  64
#define HH   96
#define WW   96
#define PP   9216            // HH*WW
#define CP   4718592         // C_*PP
#define C8P  589824          // C8_*PP
#define ATTN 1769472         // PP*192

typedef __attribute__((ext_vector_type(4))) float f32x4;
typedef __attribute__((ext_vector_type(8))) __bf16 bf16x8;
typedef __attribute__((ext_vector_type(8))) unsigned short ushort8;
typedef __attribute__((ext_vector_type(4))) unsigned short ushort4v;
typedef __attribute__((ext_vector_type(2))) unsigned short ushort2v;
typedef __attribute__((ext_vector_type(2))) float float2v;

__device__ __forceinline__ float bf2f(unsigned short u) {
    union { unsigned u; float f; } x; x.u = ((unsigned)u) << 16; return x.f;
}
__device__ __forceinline__ unsigned short f2bf(float f) {
    union { float f; unsigned u; } x; x.f = f;
    unsigned r = x.u + 0x7fffu + ((x.u >> 16) & 1u);
    return (unsigned short)(r >> 16);
}
__device__ __forceinline__ void gload16(const void* g, void* l) {
    __builtin_amdgcn_global_load_lds(
        (const __attribute__((address_space(1))) unsigned int*)g,
        (__attribute__((address_space(3))) unsigned int*)l, 16, 0, 0);
}

// ---------------- all 4 weight casts in one dispatch ----------------
__global__ __launch_bounds__(256) void cast_w(
    const float* __restrict__ Wv, const float* __restrict__ Wqv,
    const float* __restrict__ Wq, const float* __restrict__ Wk,
    unsigned short* __restrict__ oV, unsigned short* __restrict__ oQV,
    unsigned short* __restrict__ oQ, unsigned short* __restrict__ oK)
{
    int y = blockIdx.y;
    int n = (y < 2) ? 262144 : 32768;
    const float* s = (y == 0) ? Wv : (y == 1) ? Wqv : (y == 2) ? Wq : Wk;
    unsigned short* d = (y == 0) ? oV : (y == 1) ? oQV : (y == 2) ? oQ : oK;
    int i = (blockIdx.x * 256 + threadIdx.x) * 4;
    if (i < n) {
        float4 v = *(const float4*)(s + i);
        ushort4v o = { f2bf(v.x), f2bf(v.y), f2bf(v.z), f2bf(v.w) };
        *(ushort4v*)(d + i) = o;
    }
}

// ---------------- x fp32 [C][P] -> xT bf16 [P][C], both tensors ----------------
__global__ __launch_bounds__(256) void cast_transpose_cp(
    const float* __restrict__ xq, const float* __restrict__ xe,
    unsigned short* __restrict__ xTq, unsigned short* __restrict__ xTe)
{
    int zz = blockIdx.z;
    int which = zz & 1;
    size_t b = zz >> 1;
    const float* xb = (which ? xe : xq) + b * (size_t)CP;
    unsigned short* xTb = (which ? xTe : xTq) + b * (size_t)CP;
    int p0 = blockIdx.x * 64, c0 = blockIdx.y * 64;

    __shared__ unsigned short T[64][65];
    int t = threadIdx.x;
    int pp = t & 31, cg = t >> 5;
#pragma unroll
    for (int i = 0; i < 8; ++i) {
        int c = cg + 8 * i;
        float2v v = *(const float2v*)(xb + (size_t)(c0 + c) * PP + p0 + pp * 2);
        T[c][pp * 2] = f2bf(v.x);
        T[c][pp * 2 + 1] = f2bf(v.y);
    }
    __syncthreads();
    int cp = t & 31;
#pragma unroll
    for (int i = 0; i < 8; ++i) {
        int e = t + 256 * i;
        int p = e >> 5;
        ushort2v o = { T[cp * 2][p], T[cp * 2 + 1][p] };
        *(ushort2v*)(xTb + (size_t)(p0 + p) * C_ + c0 + cp * 2) = o;
    }
}

// ---------------- MFMA GEMM q & k (BM=64, bf16 out), counted-vmcnt 2-phase ----------------
// grid (72, 2, g); per-tile VMEM instrs/wave = 3 (1 A + 2 B)
__global__ __launch_bounds__(256) void gemm_qk(
    const unsigned short* __restrict__ Wqb, const unsigned short* __restrict__ Wkb,
    const unsigned short* __restrict__ xTq, const unsigned short* __restrict__ xTe,
    const float* __restrict__ bq, const float* __restrict__ bk,
    unsigned short* __restrict__ qout, unsigned short* __restrict__ kout)
{
    int sel = blockIdx.y;
    const unsigned short* A = sel ? Wkb : Wqb;
    const float* bias = sel ? bk : bq;
    int p0 = blockIdx.x * 128;
    size_t b = blockIdx.z;
    const unsigned short* Bb = (sel ? xTe : xTq) + b * (size_t)CP;
    unsigned short* outb = (sel ? kout : qout) + b * (size_t)C8P;

    __shared__ __align__(16) unsigned short Asm[2][64 * 32];
    __shared__ __align__(16) unsigned short Bsm[2][128 * 32];

    int tid = threadIdx.x;
    int lane = tid & 63, wid = tid >> 6;
    int wr = wid >> 1, wc = wid & 1;
    int l15 = lane & 15, l4 = lane >> 4;
    f32x4 acc[2][4] = {};

#define QK_STAGE(KT, BUF)                                                              \
    {                                                                                  \
        int k0s = (KT) * 32;                                                           \
        int c = tid;                                                                   \
        gload16(A + (size_t)(c >> 2) * 512 + k0s + (c & 3) * 8, Asm[BUF] + c * 8);     \
        gload16(Bb + (size_t)(p0 + (c >> 2)) * 512 + k0s + (c & 3) * 8, Bsm[BUF] + c * 8); \
        int cb = tid + 256;                                                            \
        gload16(Bb + (size_t)(p0 + (cb >> 2)) * 512 + k0s + (cb & 3) * 8, Bsm[BUF] + cb * 8); \
    }

    QK_STAGE(0, 0);
    QK_STAGE(1, 1);

#pragma unroll
    for (int k = 0; k < 16; ++k) {
        int cur = k & 1;
        if (k < 15) asm volatile("s_waitcnt vmcnt(3)" ::: "memory");
        else        asm volatile("s_waitcnt vmcnt(0)" ::: "memory");
        __builtin_amdgcn_s_barrier();
        bf16x8 af[2], bfr[4];
#pragma unroll
        for (int m = 0; m < 2; ++m)
            af[m] = *(const bf16x8*)&Asm[cur][(wr * 32 + m * 16 + l15) * 32 + l4 * 8];
#pragma unroll
        for (int n = 0; n < 4; ++n)
            bfr[n] = *(const bf16x8*)&Bsm[cur][(wc * 64 + n * 16 + l15) * 32 + l4 * 8];
#pragma unroll
        for (int m = 0; m < 2; ++m)
#pragma unroll
            for (int n = 0; n < 4; ++n)
                acc[m][n] = __builtin_amdgcn_mfma_f32_16x16x32_bf16(af[m], bfr[n], acc[m][n], 0, 0, 0);
        asm volatile("" ::: "memory");
        __builtin_amdgcn_s_barrier();
        if (k < 14) QK_STAGE(k + 2, cur);
    }
#undef QK_STAGE

#pragma unroll
    for (int m = 0; m < 2; ++m)
#pragma unroll
        for (int n = 0; n < 4; ++n) {
            int pcol = p0 + wc * 64 + n * 16 + l15;
#pragma unroll
            for (int r = 0; r < 4; ++r) {
                int orow = wr * 32 + m * 16 + l4 * 4 + r;
                outb[(size_t)orow * PP + pcol] = f2bf(acc[m][n][r] + bias[orow]);
            }
        }
}

// ---------------- bf16 96x96 spatial transpose (q,k only) ----------------
__global__ __launch_bounds__(256) void thw_b(
    const unsigned short* __restrict__ in, unsigned short* __restrict__ out)
{
    size_t m = blockIdx.x;
    const unsigned short* im = in + m * (size_t)PP;
    unsigned short* om = out + m * (size_t)PP;
    __shared__ unsigned short T[96][97];
    int t = threadIdx.x;
#pragma unroll
    for (int i = 0; i < 18; ++i) {
        int v = t + 256 * i;
        int r = v / 48, pp = v - r * 48;
        ushort2v u = *(const ushort2v*)(im + r * 96 + pp * 2);
        T[r][pp * 2] = u.x;
        T[r][pp * 2 + 1] = u.y;
    }
    __syncthreads();
#pragma unroll
    for (int i = 0; i < 18; ++i) {
        int v = t + 256 * i;
        int w = v / 48, hh = v - w * 48;
        ushort2v o = { T[hh * 2][w], T[hh * 2 + 1][w] };
        *(ushort2v*)(om + w * 96 + hh * 2) = o;
    }
}

// ---------------- scores + exp + row-partial-sums: grid (96, 2, g) ----------------
__global__ __launch_bounds__(256) void scores_kernel(
    const unsigned short* __restrict__ qT, const unsigned short* __restrict__ kT,
    const unsigned short* __restrict__ q, const unsigned short* __restrict__ k,
    unsigned short* __restrict__ attb, float* __restrict__ rsum0, float* __restrict__ rsum1)
{
    int s = blockIdx.x;
    int ori = blockIdx.y;
    size_t b = blockIdx.z;
    const unsigned short* qs = (ori ? q : qT) + b * (size_t)C8P;
    const unsigned short* ks = (ori ? k : kT) + b * (size_t)C8P;
    unsigned short* ab = attb + b * (size_t)ATTN;
    float* rs = (ori ? rsum1 : rsum0) + b * (size_t)PP;

    __shared__ float Qs[64][97];
    __shared__ float Ks[64][97];
    int t = threadIdx.x;
    for (int v = t; v < 64 * 12; v += 256) {
        int c = v / 12, gg = v - c * 12;
        size_t gi = (size_t)c * PP + (size_t)s * 96 + gg * 8;
        ushort8 uq = *(const ushort8*)(qs + gi);
        ushort8 uk = *(const ushort8*)(ks + gi);
#pragma unroll
        for (int kk = 0; kk < 8; ++kk) {
            Qs[c][gg * 8 + kk] = bf2f(uq[kk]);
            Ks[c][gg * 8 + kk] = bf2f(uk[kk]);
        }
    }
    __syncthreads();
    int tx = t & 15, ty = t >> 4;
    float acc[6][6] = {};
    for (int c = 0; c < 64; ++c) {
        float qf[6], kf[6];
#pragma unroll
        for (int i = 0; i < 6; ++i) { qf[i] = Qs[c][ty + 16 * i]; kf[i] = Ks[c][tx + 16 * i]; }
#pragma unroll
        for (int i = 0; i < 6; ++i)
#pragma unroll
            for (int j = 0; j < 6; ++j) acc[i][j] = fmaf(qf[i], kf[j], acc[i][j]);
    }
#pragma unroll
    for (int i = 0; i < 6; ++i) {
        int m = ty + 16 * i;
        size_t row = ori ? ((size_t)s * 96 + m) : ((size_t)m * 96 + s);
        unsigned short* rowp = ab + row * 192 + (ori ? 96 : 0);
        float part = 0.0f;
#pragma unroll
        for (int j = 0; j < 6; ++j) {
            int jj = tx + 16 * j;
            float e = (!ori && jj == m) ? 0.0f : __expf(acc[i][j] - 20.0f);
            part += e;
            rowp[jj] = f2bf(e);
        }
#pragma unroll
        for (int off = 1; off < 16; off <<= 1) part += __shfl_xor(part, off);
        if (tx == 0) rs[row] = part;
    }
}

// ---------------- MFMA apply on x (staged from xT, XOR-swizzled): yT[p][c] ----------------
// grid (96 s, 4 = path*2+ct, g), 512 thr = 8 waves (2 m x 4 n)
template<int ORI>
__global__ __launch_bounds__(512) void apply_mfma(
    const unsigned short* __restrict__ xT_e, const unsigned short* __restrict__ xT_q,
    unsigned short* __restrict__ yT_e, unsigned short* __restrict__ yT_q,
    const unsigned short* __restrict__ attb,
    const float* __restrict__ rsum0, const float* __restrict__ rsum1)
{
    int s = blockIdx.x;
    int path = blockIdx.y >> 1, ct = blockIdx.y & 1;
    int c0 = ct * 256;
    size_t b = blockIdx.z;
    const unsigned short* X = (path ? xT_q : xT_e) + b * (size_t)CP;
    unsigned short* Y = (path ? yT_q : yT_e) + b * (size_t)CP;
    const unsigned short* ab = attb + b * (size_t)ATTN;
    const float* r0 = rsum0 + b * (size_t)PP;
    const float* r1 = rsum1 + b * (size_t)PP;

    __shared__ __align__(16) unsigned short Att[96][104];
    __shared__ __align__(16) unsigned short Xs[256][104];   // [c][j], col-group XOR-swizzled by (c>>3)&3

    int tid = threadIdx.x;
    for (int v = tid; v < 96 * 12; v += 512) {
        int r = v / 12, gg = v - r * 12;
        size_t base = ORI ? ((size_t)(s * 96 + r) * 192 + 96) : ((size_t)(r * 96 + s) * 192);
        *(ushort8*)&Att[r][gg * 8] = *(const ushort8*)(ab + base + gg * 8);
    }
    for (int v = tid; v < 96 * 32; v += 512) {
        int j = v >> 5, cc = v & 31;
        size_t pj = ORI ? ((size_t)s * 96 + j) : ((size_t)j * 96 + s);
        ushort8 u = *(const ushort8*)(X + pj * C_ + c0 + cc * 8);
        int js = j ^ ((cc & 3) << 3);
#pragma unroll
        for (int e = 0; e < 8; ++e) Xs[cc * 8 + e][js] = u[e];
    }
    __syncthreads();

    int lane = tid & 63, wid = tid >> 6;
    int wm = wid >> 2, wn = wid & 3;
    int l15 = lane & 15, l4 = lane >> 4;
    f32x4 acc[3][4] = {};
#pragma unroll
    for (int k = 0; k < 3; ++k) {
        bf16x8 a[3], xx[4];
#pragma unroll
        for (int mi = 0; mi < 3; ++mi)
            a[mi] = *(const bf16x8*)&Att[wm * 48 + mi * 16 + l15][k * 32 + l4 * 8];
#pragma unroll
        for (int ni = 0; ni < 4; ++ni) {
            int row = wn * 64 + ni * 16 + l15;
            int gsw = (k * 4 + l4) ^ ((row >> 3) & 3);
            xx[ni] = *(const bf16x8*)&Xs[row][gsw * 8];
        }
#pragma unroll
        for (int mi = 0; mi < 3; ++mi)
#pragma unroll
            for (int ni = 0; ni < 4; ++ni)
                acc[mi][ni] = __builtin_amdgcn_mfma_f32_16x16x32_bf16(a[mi], xx[ni], acc[mi][ni], 0, 0, 0);
    }

#pragma unroll
    for (int mi = 0; mi < 3; ++mi) {
#pragma unroll
        for (int r = 0; r < 4; ++r) {
            int mrow = wm * 48 + mi * 16 + l4 * 4 + r;
            size_t p = ORI ? ((size_t)s * 96 + mrow) : ((size_t)mrow * 96 + s);
            float rinv = 0.0f;
            if (ORI) rinv = 1.0f / (r0[p] + r1[p]);
            size_t base = p * C_ + c0;
#pragma unroll
            for (int ni = 0; ni < 4; ++ni) {
                size_t idx = base + wn * 64 + ni * 16 + l15;
                if (ORI == 0) {
                    Y[idx] = f2bf(acc[mi][ni][r]);
                } else {
                    float tot = bf2f(Y[idx]) + acc[mi][ni][r];
                    Y[idx] = f2bf(tot * rinv);
                }
            }
        }
    }
}

// ---------------- final GEMM + fused epilogue: 512 thr, BK=64, swizzle, counted-vmcnt dbuf,
//                  x-residual prefetched in 4-load chunks inside the K-loop ----------------
// grid (72, 8, g); y = path*4 + ot; per-tile VMEM instrs/wave = 4
__global__ __launch_bounds__(512) void gemm_out(
    const unsigned short* __restrict__ Wvb, const unsigned short* __restrict__ Wqvb,
    const unsigned short* __restrict__ yT_e, const unsigned short* __restrict__ yT_q,
    const float* __restrict__ bv, const float* __restrict__ bqv,
    const float* __restrict__ xe, const float* __restrict__ xq,
    const float* __restrict__ g1, const float* __restrict__ g2,
    float* __restrict__ o0, float* __restrict__ o1)
{
    int yy = blockIdx.y;
    int path = yy >> 2, ot = yy & 3;
    const unsigned short* A = path ? Wqvb : Wvb;
    const float* bias = path ? bqv : bv;
    int p0 = blockIdx.x * 128;
    int o0r = ot * 128;
    size_t b = blockIdx.z;
    const unsigned short* Bb = (path ? yT_q : yT_e) + b * (size_t)CP;
    const float* xb = (path ? xq : xe) + b * (size_t)CP;
    float* ob = (path ? o1 : o0) + b * (size_t)CP;
    float gam = (path ? g2 : g1)[0];

    __shared__ __align__(16) unsigned short Asm[2][128 * 64];
    __shared__ __align__(16) unsigned short Bsm[2][128 * 64];

    int tid = threadIdx.x;             // 0..511, 8 waves
    int lane = tid & 63, wid = tid >> 6;
    int wr = wid >> 2, wc = wid & 3;   // 2 x 4 wave grid; wave tile 64 rows x 32 cols
    int l15 = lane & 15, l4 = lane >> 4;
    f32x4 acc[4][2] = {};
    float xv[4][2][4];                 // prefetched x residual (static-indexed, stays in VGPRs)

#define GO_STAGE(KT, BUF)                                                                  \
    {                                                                                      \
        int k0s = (KT) * 64;                                                               \
        _Pragma("unroll")                                                                  \
        for (int i = 0; i < 2; ++i) {                                                      \
            int ch = tid + i * 512;                                                        \
            int row = ch >> 3, slot = ch & 7;                                              \
            int gs = slot ^ (row & 7);                                                     \
            gload16(A + (size_t)(o0r + row) * 512 + k0s + gs * 8, Asm[BUF] + ch * 8);      \
            gload16(Bb + (size_t)(p0 + row) * 512 + k0s + gs * 8, Bsm[BUF] + ch * 8);      \
        }                                                                                  \
    }

    GO_STAGE(0, 0);
    GO_STAGE(1, 1);

#pragma unroll
    for (int k = 0; k < 8; ++k) {
        int cur = k & 1;
        // issue-order: s0,s1 | k0: x0,s2 | k1: x1,s3 | ... | k5: x5,s7 | k6: x6 | k7: x7
        if (k == 0)      asm volatile("s_waitcnt vmcnt(4)" ::: "memory");
        else if (k < 7)  asm volatile("s_waitcnt vmcnt(8)" ::: "memory");
        else             asm volatile("s_waitcnt vmcnt(4)" ::: "memory");
        __builtin_amdgcn_s_barrier();
#pragma unroll
        for (int ks = 0; ks < 2; ++ks) {
            bf16x8 af[4], bfr[2];
#pragma unroll
            for (int m = 0; m < 4; ++m) {
                int row = wr * 64 + m * 16 + l15;
                int sl = (ks * 4 + l4) ^ (row & 7);
                af[m] = *(const bf16x8*)&Asm[cur][row * 64 + sl * 8];
            }
#pragma unroll
            for (int n = 0; n < 2; ++n) {
                int row = wc * 32 + n * 16 + l15;
                int sl = (ks * 4 + l4) ^ (row & 7);
                bfr[n] = *(const bf16x8*)&Bsm[cur][row * 64 + sl * 8];
            }
#pragma unroll
            for (int m = 0; m < 4; ++m)
#pragma unroll
                for (int n = 0; n < 2; ++n)
                    acc[m][n] = __builtin_amdgcn_mfma_f32_16x16x32_bf16(af[m], bfr[n], acc[m][n], 0, 0, 0);
        }
        asm volatile("" ::: "memory");
        __builtin_amdgcn_s_barrier();
        {   // x-prefetch chunk k: fragment (m = k>>1, n = k&1), 4 dword loads
            int xm = k >> 1, xn = k & 1;
            int pcol = p0 + wc * 32 + xn * 16 + l15;
#pragma unroll
            for (int r = 0; r < 4; ++r) {
                int orow = o0r + wr * 64 + xm * 16 + l4 * 4 + r;
                xv[xm][xn][r] = xb[(size_t)orow * PP + pcol];
            }
        }
        if (k < 6) GO_STAGE(k + 2, cur);
    }
#undef GO_STAGE
    asm volatile("s_waitcnt vmcnt(0)" ::: "memory");

#pragma unroll
    for (int m = 0; m < 4; ++m)
#pragma unroll
        for (int n = 0; n < 2; ++n) {
            int pcol = p0 + wc * 32 + n * 16 + l15;
#pragma unroll
            for (int r = 0; r < 4; ++r) {
                int orow = o0r + wr * 64 + m * 16 + l4 * 4 + r;
                size_t idx = (size_t)orow * PP + pcol;
                float val = acc[m][n][r] + bias[orow];
                ob[idx] = gam * (val + 2.0f) + xv[m][n][r];
            }
        }
}

extern "C" void kernel_launch(void* const* d_in, const int* in_sizes, int n_in,
                              void* d_out, int out_size, void* d_ws, size_t ws_size,
                              hipStream_t stream)
{
    const float* x_ex = (const float*)d_in[0];
    const float* x_q  = (const float*)d_in[1];
    const float* Wq   = (const float*)d_in[2];
    const float* bq   = (const float*)d_in[3];
    const float* Wk   = (const float*)d_in[4];
    const float* bk   = (const float*)d_in[5];
    const float* Wv   = (const float*)d_in[6];
    const float* bv   = (const float*)d_in[7];
    const float* Wqv  = (const float*)d_in[8];
    const float* bqv  = (const float*)d_in[9];
    const float* g1   = (const float*)d_in[10];
    const float* g2   = (const float*)d_in[11];
    float* out0 = (float*)d_out;
    float* out1 = out0 + (size_t)8 * CP;

    unsigned short* hp = (unsigned short*)d_ws;
    unsigned short* Wvb  = hp; hp += 262144;
    unsigned short* Wqvb = hp; hp += 262144;
    unsigned short* Wqb  = hp; hp += 32768;
    unsigned short* Wkb  = hp; hp += 32768;
    size_t head = (size_t)(hp - (unsigned short*)d_ws) * 2;

    size_t perB = 4ull * CP + (size_t)ATTN + 4ull * C8P + 4ull * PP;
    int g = 8;
    while (g > 1 && head + (size_t)g * perB * 2 > ws_size) g >>= 1;

    unsigned short* p = hp;
    unsigned short* xT_e = p; p += (size_t)g * CP;
    unsigned short* xT_q = p; p += (size_t)g * CP;
    unsigned short* yT_e = p; p += (size_t)g * CP;
    unsigned short* yT_q = p; p += (size_t)g * CP;
    unsigned short* attb = p; p += (size_t)g * ATTN;
    unsigned short* qb   = p; p += (size_t)g * C8P;
    unsigned short* kb   = p; p += (size_t)g * C8P;  // adjacent to qb
    unsigned short* qTb  = p; p += (size_t)g * C8P;
    unsigned short* kTb  = p; p += (size_t)g * C8P;  // adjacent to qTb
    float* rsum0 = (float*)p; p += (size_t)g * PP * 2;
    float* rsum1 = (float*)p; p += (size_t)g * PP * 2;

    cast_w<<<dim3(256, 4), 256, 0, stream>>>(Wv, Wqv, Wq, Wk, Wvb, Wqvb, Wqb, Wkb);

    for (int b0 = 0; b0 < 8; b0 += g) {
        const float* xe = x_ex + (size_t)b0 * CP;
        const float* xq = x_q  + (size_t)b0 * CP;
        float* o0 = out0 + (size_t)b0 * CP;
        float* o1 = out1 + (size_t)b0 * CP;

        cast_transpose_cp<<<dim3(144, 8, 2 * g), 256, 0, stream>>>(xq, xe, xT_q, xT_e);
        gemm_qk<<<dim3(72, 2, g), 256, 0, stream>>>(Wqb, Wkb, xT_q, xT_e, bq, bk, qb, kb);
        thw_b<<<dim3(2 * g * 64), 256, 0, stream>>>(qb, qTb);
        scores_kernel<<<dim3(96, 2, g), 256, 0, stream>>>(qTb, kTb, qb, kb, attb, rsum0, rsum1);
        apply_mfma<0><<<dim3(96, 4, g), 512, 0, stream>>>(xT_e, xT_q, yT_e, yT_q, attb, rsum0, rsum1);
        apply_mfma<1><<<dim3(96, 4, g), 512, 0, stream>>>(xT_e, xT_q, yT_e, yT_q, attb, rsum0, rsum1);
        gemm_out<<<dim3(72, 8, g), 512, 0, stream>>>(Wvb, Wqvb, yT_e, yT_q, bv, bqv,
                                                     xe, xq, g1, g2, o0, o1);
    }
}

// Round 15
// 545.574 us; speedup vs baseline: 1.0834x; 1.0290x over previous
//
#include <hip/hip_runtime.h>
#include <math.h>

#define C_   512
#define C8_  64
#define HH   96
#define WW   96
#define PP   9216            // HH*WW
#define CP   4718592         // C_*PP
#define C8P  589824          // C8_*PP
#define ATTN 1769472         // PP*192

typedef __attribute__((ext_vector_type(4))) float f32x4;
typedef __attribute__((ext_vector_type(8))) __bf16 bf16x8;
typedef __attribute__((ext_vector_type(8))) unsigned short ushort8;
typedef __attribute__((ext_vector_type(4))) unsigned short ushort4v;
typedef __attribute__((ext_vector_type(2))) unsigned short ushort2v;
typedef __attribute__((ext_vector_type(2))) float float2v;

__device__ __forceinline__ float bf2f(unsigned short u) {
    union { unsigned u; float f; } x; x.u = ((unsigned)u) << 16; return x.f;
}
__device__ __forceinline__ unsigned short f2bf(float f) {
    union { float f; unsigned u; } x; x.f = f;
    unsigned r = x.u + 0x7fffu + ((x.u >> 16) & 1u);
    return (unsigned short)(r >> 16);
}
__device__ __forceinline__ void gload16(const void* g, void* l) {
    __builtin_amdgcn_global_load_lds(
        (const __attribute__((address_space(1))) unsigned int*)g,
        (__attribute__((address_space(3))) unsigned int*)l, 16, 0, 0);
}

// ---------------- all 4 weight casts in one dispatch ----------------
__global__ __launch_bounds__(256) void cast_w(
    const float* __restrict__ Wv, const float* __restrict__ Wqv,
    const float* __restrict__ Wq, const float* __restrict__ Wk,
    unsigned short* __restrict__ oV, unsigned short* __restrict__ oQV,
    unsigned short* __restrict__ oQ, unsigned short* __restrict__ oK)
{
    int y = blockIdx.y;
    int n = (y < 2) ? 262144 : 32768;
    const float* s = (y == 0) ? Wv : (y == 1) ? Wqv : (y == 2) ? Wq : Wk;
    unsigned short* d = (y == 0) ? oV : (y == 1) ? oQV : (y == 2) ? oQ : oK;
    int i = (blockIdx.x * 256 + threadIdx.x) * 4;
    if (i < n) {
        float4 v = *(const float4*)(s + i);
        ushort4v o = { f2bf(v.x), f2bf(v.y), f2bf(v.z), f2bf(v.w) };
        *(ushort4v*)(d + i) = o;
    }
}

// ---------------- x fp32 [C][P] -> xT bf16 [P][C], both tensors ----------------
__global__ __launch_bounds__(256) void cast_transpose_cp(
    const float* __restrict__ xq, const float* __restrict__ xe,
    unsigned short* __restrict__ xTq, unsigned short* __restrict__ xTe)
{
    int zz = blockIdx.z;
    int which = zz & 1;
    size_t b = zz >> 1;
    const float* xb = (which ? xe : xq) + b * (size_t)CP;
    unsigned short* xTb = (which ? xTe : xTq) + b * (size_t)CP;
    int p0 = blockIdx.x * 64, c0 = blockIdx.y * 64;

    __shared__ unsigned short T[64][65];
    int t = threadIdx.x;
    int pp = t & 31, cg = t >> 5;
#pragma unroll
    for (int i = 0; i < 8; ++i) {
        int c = cg + 8 * i;
        float2v v = *(const float2v*)(xb + (size_t)(c0 + c) * PP + p0 + pp * 2);
        T[c][pp * 2] = f2bf(v.x);
        T[c][pp * 2 + 1] = f2bf(v.y);
    }
    __syncthreads();
    int cp = t & 31;
#pragma unroll
    for (int i = 0; i < 8; ++i) {
        int e = t + 256 * i;
        int p = e >> 5;
        ushort2v o = { T[cp * 2][p], T[cp * 2 + 1][p] };
        *(ushort2v*)(xTb + (size_t)(p0 + p) * C_ + c0 + cp * 2) = o;
    }
}

// ---------------- MFMA GEMM q & k (BM=64, bf16 out), counted-vmcnt 2-phase ----------------
__global__ __launch_bounds__(256) void gemm_qk(
    const unsigned short* __restrict__ Wqb, const unsigned short* __restrict__ Wkb,
    const unsigned short* __restrict__ xTq, const unsigned short* __restrict__ xTe,
    const float* __restrict__ bq, const float* __restrict__ bk,
    unsigned short* __restrict__ qout, unsigned short* __restrict__ kout)
{
    int sel = blockIdx.y;
    const unsigned short* A = sel ? Wkb : Wqb;
    const float* bias = sel ? bk : bq;
    int p0 = blockIdx.x * 128;
    size_t b = blockIdx.z;
    const unsigned short* Bb = (sel ? xTe : xTq) + b * (size_t)CP;
    unsigned short* outb = (sel ? kout : qout) + b * (size_t)C8P;

    __shared__ __align__(16) unsigned short Asm[2][64 * 32];
    __shared__ __align__(16) unsigned short Bsm[2][128 * 32];

    int tid = threadIdx.x;
    int lane = tid & 63, wid = tid >> 6;
    int wr = wid >> 1, wc = wid & 1;
    int l15 = lane & 15, l4 = lane >> 4;
    f32x4 acc[2][4] = {};

#define QK_STAGE(KT, BUF)                                                              \
    {                                                                                  \
        int k0s = (KT) * 32;                                                           \
        int c = tid;                                                                   \
        gload16(A + (size_t)(c >> 2) * 512 + k0s + (c & 3) * 8, Asm[BUF] + c * 8);     \
        gload16(Bb + (size_t)(p0 + (c >> 2)) * 512 + k0s + (c & 3) * 8, Bsm[BUF] + c * 8); \
        int cb = tid + 256;                                                            \
        gload16(Bb + (size_t)(p0 + (cb >> 2)) * 512 + k0s + (cb & 3) * 8, Bsm[BUF] + cb * 8); \
    }

    QK_STAGE(0, 0);
    QK_STAGE(1, 1);

#pragma unroll
    for (int k = 0; k < 16; ++k) {
        int cur = k & 1;
        if (k < 15) asm volatile("s_waitcnt vmcnt(3)" ::: "memory");
        else        asm volatile("s_waitcnt vmcnt(0)" ::: "memory");
        __builtin_amdgcn_s_barrier();
        bf16x8 af[2], bfr[4];
#pragma unroll
        for (int m = 0; m < 2; ++m)
            af[m] = *(const bf16x8*)&Asm[cur][(wr * 32 + m * 16 + l15) * 32 + l4 * 8];
#pragma unroll
        for (int n = 0; n < 4; ++n)
            bfr[n] = *(const bf16x8*)&Bsm[cur][(wc * 64 + n * 16 + l15) * 32 + l4 * 8];
#pragma unroll
        for (int m = 0; m < 2; ++m)
#pragma unroll
            for (int n = 0; n < 4; ++n)
                acc[m][n] = __builtin_amdgcn_mfma_f32_16x16x32_bf16(af[m], bfr[n], acc[m][n], 0, 0, 0);
        asm volatile("" ::: "memory");
        __builtin_amdgcn_s_barrier();
        if (k < 14) QK_STAGE(k + 2, cur);
    }
#undef QK_STAGE

#pragma unroll
    for (int m = 0; m < 2; ++m)
#pragma unroll
        for (int n = 0; n < 4; ++n) {
            int pcol = p0 + wc * 64 + n * 16 + l15;
#pragma unroll
            for (int r = 0; r < 4; ++r) {
                int orow = wr * 32 + m * 16 + l4 * 4 + r;
                outb[(size_t)orow * PP + pcol] = f2bf(acc[m][n][r] + bias[orow]);
            }
        }
}

// ---------------- bf16 96x96 spatial transpose (q,k only) ----------------
__global__ __launch_bounds__(256) void thw_b(
    const unsigned short* __restrict__ in, unsigned short* __restrict__ out)
{
    size_t m = blockIdx.x;
    const unsigned short* im = in + m * (size_t)PP;
    unsigned short* om = out + m * (size_t)PP;
    __shared__ unsigned short T[96][97];
    int t = threadIdx.x;
#pragma unroll
    for (int i = 0; i < 18; ++i) {
        int v = t + 256 * i;
        int r = v / 48, pp = v - r * 48;
        ushort2v u = *(const ushort2v*)(im + r * 96 + pp * 2);
        T[r][pp * 2] = u.x;
        T[r][pp * 2 + 1] = u.y;
    }
    __syncthreads();
#pragma unroll
    for (int i = 0; i < 18; ++i) {
        int v = t + 256 * i;
        int w = v / 48, hh = v - w * 48;
        ushort2v o = { T[hh * 2][w], T[hh * 2 + 1][w] };
        *(ushort2v*)(om + w * 96 + hh * 2) = o;
    }
}

// ---------------- scores + exp + row-partial-sums: grid (96, 2, g) ----------------
__global__ __launch_bounds__(256) void scores_kernel(
    const unsigned short* __restrict__ qT, const unsigned short* __restrict__ kT,
    const unsigned short* __restrict__ q, const unsigned short* __restrict__ k,
    unsigned short* __restrict__ attb, float* __restrict__ rsum0, float* __restrict__ rsum1)
{
    int s = blockIdx.x;
    int ori = blockIdx.y;
    size_t b = blockIdx.z;
    const unsigned short* qs = (ori ? q : qT) + b * (size_t)C8P;
    const unsigned short* ks = (ori ? k : kT) + b * (size_t)C8P;
    unsigned short* ab = attb + b * (size_t)ATTN;
    float* rs = (ori ? rsum1 : rsum0) + b * (size_t)PP;

    __shared__ float Qs[64][97];
    __shared__ float Ks[64][97];
    int t = threadIdx.x;
    for (int v = t; v < 64 * 12; v += 256) {
        int c = v / 12, gg = v - c * 12;
        size_t gi = (size_t)c * PP + (size_t)s * 96 + gg * 8;
        ushort8 uq = *(const ushort8*)(qs + gi);
        ushort8 uk = *(const ushort8*)(ks + gi);
#pragma unroll
        for (int kk = 0; kk < 8; ++kk) {
            Qs[c][gg * 8 + kk] = bf2f(uq[kk]);
            Ks[c][gg * 8 + kk] = bf2f(uk[kk]);
        }
    }
    __syncthreads();
    int tx = t & 15, ty = t >> 4;
    float acc[6][6] = {};
    for (int c = 0; c < 64; ++c) {
        float qf[6], kf[6];
#pragma unroll
        for (int i = 0; i < 6; ++i) { qf[i] = Qs[c][ty + 16 * i]; kf[i] = Ks[c][tx + 16 * i]; }
#pragma unroll
        for (int i = 0; i < 6; ++i)
#pragma unroll
            for (int j = 0; j < 6; ++j) acc[i][j] = fmaf(qf[i], kf[j], acc[i][j]);
    }
#pragma unroll
    for (int i = 0; i < 6; ++i) {
        int m = ty + 16 * i;
        size_t row = ori ? ((size_t)s * 96 + m) : ((size_t)m * 96 + s);
        unsigned short* rowp = ab + row * 192 + (ori ? 96 : 0);
        float part = 0.0f;
#pragma unroll
        for (int j = 0; j < 6; ++j) {
            int jj = tx + 16 * j;
            float e = (!ori && jj == m) ? 0.0f : __expf(acc[i][j] - 20.0f);
            part += e;
            rowp[jj] = f2bf(e);
        }
#pragma unroll
        for (int off = 1; off < 16; off <<= 1) part += __shfl_xor(part, off);
        if (tx == 0) rs[row] = part;
    }
}

// ---------------- MFMA apply on x (staged from xT, XOR-swizzled): yT[p][c] ----------------
// grid (96 s, 4 = path*2+ct, g), 512 thr = 8 waves (2 m x 4 n)
// Epilogue repacks acc through LDS (reusing Xs) for coalesced ushort8 Y stores / RMW.
template<int ORI>
__global__ __launch_bounds__(512) void apply_mfma(
    const unsigned short* __restrict__ xT_e, const unsigned short* __restrict__ xT_q,
    unsigned short* __restrict__ yT_e, unsigned short* __restrict__ yT_q,
    const unsigned short* __restrict__ attb,
    const float* __restrict__ rsum0, const float* __restrict__ rsum1)
{
    int s = blockIdx.x;
    int path = blockIdx.y >> 1, ct = blockIdx.y & 1;
    int c0 = ct * 256;
    size_t b = blockIdx.z;
    const unsigned short* X = (path ? xT_q : xT_e) + b * (size_t)CP;
    unsigned short* Y = (path ? yT_q : yT_e) + b * (size_t)CP;
    const unsigned short* ab = attb + b * (size_t)ATTN;
    const float* r0 = rsum0 + b * (size_t)PP;
    const float* r1 = rsum1 + b * (size_t)PP;

    __shared__ __align__(16) unsigned short Att[96][104];
    __shared__ __align__(16) unsigned short Xs[256][104];   // [c][j] swizzled; reused as Wf[96][268]
    __shared__ float rs_[96];

    int tid = threadIdx.x;
    for (int v = tid; v < 96 * 12; v += 512) {
        int r = v / 12, gg = v - r * 12;
        size_t base = ORI ? ((size_t)(s * 96 + r) * 192 + 96) : ((size_t)(r * 96 + s) * 192);
        *(ushort8*)&Att[r][gg * 8] = *(const ushort8*)(ab + base + gg * 8);
    }
    for (int v = tid; v < 96 * 32; v += 512) {
        int j = v >> 5, cc = v & 31;
        size_t pj = ORI ? ((size_t)s * 96 + j) : ((size_t)j * 96 + s);
        ushort8 u = *(const ushort8*)(X + pj * C_ + c0 + cc * 8);
        int js = j ^ ((cc & 3) << 3);
#pragma unroll
        for (int e = 0; e < 8; ++e) Xs[cc * 8 + e][js] = u[e];
    }
    if (ORI && tid < 96) {
        size_t p = (size_t)s * 96 + tid;
        rs_[tid] = 1.0f / (r0[p] + r1[p]);
    }
    __syncthreads();

    int lane = tid & 63, wid = tid >> 6;
    int wm = wid >> 2, wn = wid & 3;
    int l15 = lane & 15, l4 = lane >> 4;
    f32x4 acc[3][4] = {};
#pragma unroll
    for (int k = 0; k < 3; ++k) {
        bf16x8 a[3], xx[4];
#pragma unroll
        for (int mi = 0; mi < 3; ++mi)
            a[mi] = *(const bf16x8*)&Att[wm * 48 + mi * 16 + l15][k * 32 + l4 * 8];
#pragma unroll
        for (int ni = 0; ni < 4; ++ni) {
            int row = wn * 64 + ni * 16 + l15;
            int gsw = (k * 4 + l4) ^ ((row >> 3) & 3);
            xx[ni] = *(const bf16x8*)&Xs[row][gsw * 8];
        }
#pragma unroll
        for (int mi = 0; mi < 3; ++mi)
#pragma unroll
            for (int ni = 0; ni < 4; ++ni)
                acc[mi][ni] = __builtin_amdgcn_mfma_f32_16x16x32_bf16(a[mi], xx[ni], acc[mi][ni], 0, 0, 0);
    }

    // ---- repack epilogue ----
    unsigned short* Wf = &Xs[0][0];     // row stride 268 u16 (bank-clean: l4 offsets {0,24,16,8})
    __syncthreads();                    // all Xs reads complete before overwrite
#pragma unroll
    for (int mi = 0; mi < 3; ++mi)
#pragma unroll
        for (int r = 0; r < 4; ++r) {
            int mrow = wm * 48 + mi * 16 + l4 * 4 + r;
#pragma unroll
            for (int ni = 0; ni < 4; ++ni)
                Wf[mrow * 268 + wn * 64 + ni * 16 + l15] = f2bf(acc[mi][ni][r]);
        }
    __syncthreads();
#pragma unroll
    for (int i = 0; i < 6; ++i) {
        int id = tid + 512 * i;          // 3072 chunks = 96 rows x 32 groups of 8
        int row = id >> 5, cg = id & 31;
        ushort4v w0 = *(const ushort4v*)&Wf[row * 268 + cg * 8];
        ushort4v w1 = *(const ushort4v*)&Wf[row * 268 + cg * 8 + 4];
        size_t p = ORI ? ((size_t)s * 96 + row) : ((size_t)row * 96 + s);
        unsigned short* yp = Y + p * C_ + c0 + cg * 8;
        if (ORI == 0) {
            ushort8 o = { w0[0], w0[1], w0[2], w0[3], w1[0], w1[1], w1[2], w1[3] };
            *(ushort8*)yp = o;
        } else {
            ushort8 yo = *(const ushort8*)yp;
            float rinv = rs_[row];
            ushort8 o;
#pragma unroll
            for (int e = 0; e < 4; ++e) o[e] = f2bf((bf2f(yo[e]) + bf2f(w0[e])) * rinv);
#pragma unroll
            for (int e = 0; e < 4; ++e) o[e + 4] = f2bf((bf2f(yo[e + 4]) + bf2f(w1[e])) * rinv);
            *(ushort8*)yp = o;
        }
    }
}

// ---------------- final GEMM + fused epilogue: 512 thr, BK=64, swizzle, counted-vmcnt dbuf,
//                  x-prefetch in K-loop, XCD-bijective block remap (ot-fastest) ----------------
// grid (72, 8, g); per-tile VMEM instrs/wave = 4
__global__ __launch_bounds__(512) void gemm_out(
    const unsigned short* __restrict__ Wvb, const unsigned short* __restrict__ Wqvb,
    const unsigned short* __restrict__ yT_e, const unsigned short* __restrict__ yT_q,
    const float* __restrict__ bv, const float* __restrict__ bqv,
    const float* __restrict__ xe, const float* __restrict__ xq,
    const float* __restrict__ g1, const float* __restrict__ g2,
    float* __restrict__ o0, float* __restrict__ o1)
{
    // bijective XCD remap: 576 blocks/z, nwg%8==0; ot varies fastest within an XCD chunk
    int lin = blockIdx.x + 72 * blockIdx.y;
    int nid = (lin & 7) * 72 + (lin >> 3);
    int path = nid / 288;
    int rem = nid - path * 288;
    int ptile = rem >> 2, ot = rem & 3;

    const unsigned short* A = path ? Wqvb : Wvb;
    const float* bias = path ? bqv : bv;
    int p0 = ptile * 128;
    int o0r = ot * 128;
    size_t b = blockIdx.z;
    const unsigned short* Bb = (path ? yT_q : yT_e) + b * (size_t)CP;
    const float* xb = (path ? xq : xe) + b * (size_t)CP;
    float* ob = (path ? o1 : o0) + b * (size_t)CP;
    float gam = (path ? g2 : g1)[0];

    __shared__ __align__(16) unsigned short Asm[2][128 * 64];
    __shared__ __align__(16) unsigned short Bsm[2][128 * 64];

    int tid = threadIdx.x;             // 0..511, 8 waves
    int lane = tid & 63, wid = tid >> 6;
    int wr = wid >> 2, wc = wid & 3;   // 2 x 4 wave grid; wave tile 64 rows x 32 cols
    int l15 = lane & 15, l4 = lane >> 4;
    f32x4 acc[4][2] = {};
    float xv[4][2][4];                 // prefetched x residual (static-indexed)

#define GO_STAGE(KT, BUF)                                                                  \
    {                                                                                      \
        int k0s = (KT) * 64;                                                               \
        _Pragma("unroll")                                                                  \
        for (int i = 0; i < 2; ++i) {                                                      \
            int ch = tid + i * 512;                                                        \
            int row = ch >> 3, slot = ch & 7;                                              \
            int gs = slot ^ (row & 7);                                                     \
            gload16(A + (size_t)(o0r + row) * 512 + k0s + gs * 8, Asm[BUF] + ch * 8);      \
            gload16(Bb + (size_t)(p0 + row) * 512 + k0s + gs * 8, Bsm[BUF] + ch * 8);      \
        }                                                                                  \
    }

    GO_STAGE(0, 0);
    GO_STAGE(1, 1);

#pragma unroll
    for (int k = 0; k < 8; ++k) {
        int cur = k & 1;
        if (k == 0)      asm volatile("s_waitcnt vmcnt(4)" ::: "memory");
        else if (k < 7)  asm volatile("s_waitcnt vmcnt(8)" ::: "memory");
        else             asm volatile("s_waitcnt vmcnt(4)" ::: "memory");
        __builtin_amdgcn_s_barrier();
#pragma unroll
        for (int ks = 0; ks < 2; ++ks) {
            bf16x8 af[4], bfr[2];
#pragma unroll
            for (int m = 0; m < 4; ++m) {
                int row = wr * 64 + m * 16 + l15;
                int sl = (ks * 4 + l4) ^ (row & 7);
                af[m] = *(const bf16x8*)&Asm[cur][row * 64 + sl * 8];
            }
#pragma unroll
            for (int n = 0; n < 2; ++n) {
                int row = wc * 32 + n * 16 + l15;
                int sl = (ks * 4 + l4) ^ (row & 7);
                bfr[n] = *(const bf16x8*)&Bsm[cur][row * 64 + sl * 8];
            }
#pragma unroll
            for (int m = 0; m < 4; ++m)
#pragma unroll
                for (int n = 0; n < 2; ++n)
                    acc[m][n] = __builtin_amdgcn_mfma_f32_16x16x32_bf16(af[m], bfr[n], acc[m][n], 0, 0, 0);
        }
        asm volatile("" ::: "memory");
        __builtin_amdgcn_s_barrier();
        {   // x-prefetch chunk k: fragment (m = k>>1, n = k&1)
            int xm = k >> 1, xn = k & 1;
            int pcol = p0 + wc * 32 + xn * 16 + l15;
#pragma unroll
            for (int r = 0; r < 4; ++r) {
                int orow = o0r + wr * 64 + xm * 16 + l4 * 4 + r;
                xv[xm][xn][r] = xb[(size_t)orow * PP + pcol];
            }
        }
        if (k < 6) GO_STAGE(k + 2, cur);
    }
#undef GO_STAGE
    asm volatile("s_waitcnt vmcnt(0)" ::: "memory");

#pragma unroll
    for (int m = 0; m < 4; ++m)
#pragma unroll
        for (int n = 0; n < 2; ++n) {
            int pcol = p0 + wc * 32 + n * 16 + l15;
#pragma unroll
            for (int r = 0; r < 4; ++r) {
                int orow = o0r + wr * 64 + m * 16 + l4 * 4 + r;
                size_t idx = (size_t)orow * PP + pcol;
                float val = acc[m][n][r] + bias[orow];
                ob[idx] = gam * (val + 2.0f) + xv[m][n][r];
            }
        }
}

extern "C" void kernel_launch(void* const* d_in, const int* in_sizes, int n_in,
                              void* d_out, int out_size, void* d_ws, size_t ws_size,
                              hipStream_t stream)
{
    const float* x_ex = (const float*)d_in[0];
    const float* x_q  = (const float*)d_in[1];
    const float* Wq   = (const float*)d_in[2];
    const float* bq   = (const float*)d_in[3];
    const float* Wk   = (const float*)d_in[4];
    const float* bk   = (const float*)d_in[5];
    const float* Wv   = (const float*)d_in[6];
    const float* bv   = (const float*)d_in[7];
    const float* Wqv  = (const float*)d_in[8];
    const float* bqv  = (const float*)d_in[9];
    const float* g1   = (const float*)d_in[10];
    const float* g2   = (const float*)d_in[11];
    float* out0 = (float*)d_out;
    float* out1 = out0 + (size_t)8 * CP;

    unsigned short* hp = (unsigned short*)d_ws;
    unsigned short* Wvb  = hp; hp += 262144;
    unsigned short* Wqvb = hp; hp += 262144;
    unsigned short* Wqb  = hp; hp += 32768;
    unsigned short* Wkb  = hp; hp += 32768;
    size_t head = (size_t)(hp - (unsigned short*)d_ws) * 2;

    size_t perB = 4ull * CP + (size_t)ATTN + 4ull * C8P + 4ull * PP;
    int g = 8;
    while (g > 1 && head + (size_t)g * perB * 2 > ws_size) g >>= 1;

    unsigned short* p = hp;
    unsigned short* xT_e = p; p += (size_t)g * CP;
    unsigned short* xT_q = p; p += (size_t)g * CP;
    unsigned short* yT_e = p; p += (size_t)g * CP;
    unsigned short* yT_q = p; p += (size_t)g * CP;
    unsigned short* attb = p; p += (size_t)g * ATTN;
    unsigned short* qb   = p; p += (size_t)g * C8P;
    unsigned short* kb   = p; p += (size_t)g * C8P;  // adjacent to qb
    unsigned short* qTb  = p; p += (size_t)g * C8P;
    unsigned short* kTb  = p; p += (size_t)g * C8P;  // adjacent to qTb
    float* rsum0 = (float*)p; p += (size_t)g * PP * 2;
    float* rsum1 = (float*)p; p += (size_t)g * PP * 2;

    cast_w<<<dim3(256, 4), 256, 0, stream>>>(Wv, Wqv, Wq, Wk, Wvb, Wqvb, Wqb, Wkb);

    for (int b0 = 0; b0 < 8; b0 += g) {
        const float* xe = x_ex + (size_t)b0 * CP;
        const float* xq = x_q  + (size_t)b0 * CP;
        float* o0 = out0 + (size_t)b0 * CP;
        float* o1 = out1 + (size_t)b0 * CP;

        cast_transpose_cp<<<dim3(144, 8, 2 * g), 256, 0, stream>>>(xq, xe, xT_q, xT_e);
        gemm_qk<<<dim3(72, 2, g), 256, 0, stream>>>(Wqb, Wkb, xT_q, xT_e, bq, bk, qb, kb);
        thw_b<<<dim3(2 * g * 64), 256, 0, stream>>>(qb, qTb);
        scores_kernel<<<dim3(96, 2, g), 256, 0, stream>>>(qTb, kTb, qb, kb, attb, rsum0, rsum1);
        apply_mfma<0><<<dim3(96, 4, g), 512, 0, stream>>>(xT_e, xT_q, yT_e, yT_q, attb, rsum0, rsum1);
        apply_mfma<1><<<dim3(96, 4, g), 512, 0, stream>>>(xT_e, xT_q, yT_e, yT_q, attb, rsum0, rsum1);
        gemm_out<<<dim3(72, 8, g), 512, 0, stream>>>(Wvb, Wqvb, yT_e, yT_q, bv, bqv,
                                                     xe, xq, g1, g2, o0, o1);
    }
}

// Round 16
// 522.306 us; speedup vs baseline: 1.1317x; 1.0445x over previous
//
#include <hip/hip_runtime.h>
#include <math.h>

#define C_   512
#define C8_  64
#define HH   96
#define WW   96
#define PP   9216            // HH*WW
#define CP   4718592         // C_*PP
#define C8P  589824          // C8_*PP
#define ATTN 1769472         // PP*192

typedef __attribute__((ext_vector_type(4))) float f32x4;
typedef __attribute__((ext_vector_type(8))) __bf16 bf16x8;
typedef __attribute__((ext_vector_type(8))) unsigned short ushort8;
typedef __attribute__((ext_vector_type(4))) unsigned short ushort4v;
typedef __attribute__((ext_vector_type(2))) unsigned short ushort2v;
typedef __attribute__((ext_vector_type(2))) float float2v;

__device__ __forceinline__ float bf2f(unsigned short u) {
    union { unsigned u; float f; } x; x.u = ((unsigned)u) << 16; return x.f;
}
__device__ __forceinline__ unsigned short f2bf(float f) {
    union { float f; unsigned u; } x; x.f = f;
    unsigned r = x.u + 0x7fffu + ((x.u >> 16) & 1u);
    return (unsigned short)(r >> 16);
}
__device__ __forceinline__ void gload16(const void* g, void* l) {
    __builtin_amdgcn_global_load_lds(
        (const __attribute__((address_space(1))) unsigned int*)g,
        (__attribute__((address_space(3))) unsigned int*)l, 16, 0, 0);
}

// ---------------- all 4 weight casts in one dispatch ----------------
__global__ __launch_bounds__(256) void cast_w(
    const float* __restrict__ Wv, const float* __restrict__ Wqv,
    const float* __restrict__ Wq, const float* __restrict__ Wk,
    unsigned short* __restrict__ oV, unsigned short* __restrict__ oQV,
    unsigned short* __restrict__ oQ, unsigned short* __restrict__ oK)
{
    int y = blockIdx.y;
    int n = (y < 2) ? 262144 : 32768;
    const float* s = (y == 0) ? Wv : (y == 1) ? Wqv : (y == 2) ? Wq : Wk;
    unsigned short* d = (y == 0) ? oV : (y == 1) ? oQV : (y == 2) ? oQ : oK;
    int i = (blockIdx.x * 256 + threadIdx.x) * 4;
    if (i < n) {
        float4 v = *(const float4*)(s + i);
        ushort4v o = { f2bf(v.x), f2bf(v.y), f2bf(v.z), f2bf(v.w) };
        *(ushort4v*)(d + i) = o;
    }
}

// ---------------- x fp32 [C][P] -> xT bf16 [P][C], both tensors ----------------
__global__ __launch_bounds__(256) void cast_transpose_cp(
    const float* __restrict__ xq, const float* __restrict__ xe,
    unsigned short* __restrict__ xTq, unsigned short* __restrict__ xTe)
{
    int zz = blockIdx.z;
    int which = zz & 1;
    size_t b = zz >> 1;
    const float* xb = (which ? xe : xq) + b * (size_t)CP;
    unsigned short* xTb = (which ? xTe : xTq) + b * (size_t)CP;
    int p0 = blockIdx.x * 64, c0 = blockIdx.y * 64;

    __shared__ unsigned short T[64][65];
    int t = threadIdx.x;
    int pp = t & 31, cg = t >> 5;
#pragma unroll
    for (int i = 0; i < 8; ++i) {
        int c = cg + 8 * i;
        float2v v = *(const float2v*)(xb + (size_t)(c0 + c) * PP + p0 + pp * 2);
        T[c][pp * 2] = f2bf(v.x);
        T[c][pp * 2 + 1] = f2bf(v.y);
    }
    __syncthreads();
    int cp = t & 31;
#pragma unroll
    for (int i = 0; i < 8; ++i) {
        int e = t + 256 * i;
        int p = e >> 5;
        ushort2v o = { T[cp * 2][p], T[cp * 2 + 1][p] };
        *(ushort2v*)(xTb + (size_t)(p0 + p) * C_ + c0 + cp * 2) = o;
    }
}

// ---------------- MFMA GEMM q & k (BM=64, bf16 out), counted-vmcnt 2-phase ----------------
__global__ __launch_bounds__(256) void gemm_qk(
    const unsigned short* __restrict__ Wqb, const unsigned short* __restrict__ Wkb,
    const unsigned short* __restrict__ xTq, const unsigned short* __restrict__ xTe,
    const float* __restrict__ bq, const float* __restrict__ bk,
    unsigned short* __restrict__ qout, unsigned short* __restrict__ kout)
{
    int sel = blockIdx.y;
    const unsigned short* A = sel ? Wkb : Wqb;
    const float* bias = sel ? bk : bq;
    int p0 = blockIdx.x * 128;
    size_t b = blockIdx.z;
    const unsigned short* Bb = (sel ? xTe : xTq) + b * (size_t)CP;
    unsigned short* outb = (sel ? kout : qout) + b * (size_t)C8P;

    __shared__ __align__(16) unsigned short Asm[2][64 * 32];
    __shared__ __align__(16) unsigned short Bsm[2][128 * 32];

    int tid = threadIdx.x;
    int lane = tid & 63, wid = tid >> 6;
    int wr = wid >> 1, wc = wid & 1;
    int l15 = lane & 15, l4 = lane >> 4;
    f32x4 acc[2][4] = {};

#define QK_STAGE(KT, BUF)                                                              \
    {                                                                                  \
        int k0s = (KT) * 32;                                                           \
        int c = tid;                                                                   \
        gload16(A + (size_t)(c >> 2) * 512 + k0s + (c & 3) * 8, Asm[BUF] + c * 8);     \
        gload16(Bb + (size_t)(p0 + (c >> 2)) * 512 + k0s + (c & 3) * 8, Bsm[BUF] + c * 8); \
        int cb = tid + 256;                                                            \
        gload16(Bb + (size_t)(p0 + (cb >> 2)) * 512 + k0s + (cb & 3) * 8, Bsm[BUF] + cb * 8); \
    }

    QK_STAGE(0, 0);
    QK_STAGE(1, 1);

#pragma unroll
    for (int k = 0; k < 16; ++k) {
        int cur = k & 1;
        if (k < 15) asm volatile("s_waitcnt vmcnt(3)" ::: "memory");
        else        asm volatile("s_waitcnt vmcnt(0)" ::: "memory");
        __builtin_amdgcn_s_barrier();
        bf16x8 af[2], bfr[4];
#pragma unroll
        for (int m = 0; m < 2; ++m)
            af[m] = *(const bf16x8*)&Asm[cur][(wr * 32 + m * 16 + l15) * 32 + l4 * 8];
#pragma unroll
        for (int n = 0; n < 4; ++n)
            bfr[n] = *(const bf16x8*)&Bsm[cur][(wc * 64 + n * 16 + l15) * 32 + l4 * 8];
#pragma unroll
        for (int m = 0; m < 2; ++m)
#pragma unroll
            for (int n = 0; n < 4; ++n)
                acc[m][n] = __builtin_amdgcn_mfma_f32_16x16x32_bf16(af[m], bfr[n], acc[m][n], 0, 0, 0);
        asm volatile("" ::: "memory");
        __builtin_amdgcn_s_barrier();
        if (k < 14) QK_STAGE(k + 2, cur);
    }
#undef QK_STAGE

#pragma unroll
    for (int m = 0; m < 2; ++m)
#pragma unroll
        for (int n = 0; n < 4; ++n) {
            int pcol = p0 + wc * 64 + n * 16 + l15;
#pragma unroll
            for (int r = 0; r < 4; ++r) {
                int orow = wr * 32 + m * 16 + l4 * 4 + r;
                outb[(size_t)orow * PP + pcol] = f2bf(acc[m][n][r] + bias[orow]);
            }
        }
}

// ---------------- bf16 96x96 spatial transpose (q,k only) ----------------
__global__ __launch_bounds__(256) void thw_b(
    const unsigned short* __restrict__ in, unsigned short* __restrict__ out)
{
    size_t m = blockIdx.x;
    const unsigned short* im = in + m * (size_t)PP;
    unsigned short* om = out + m * (size_t)PP;
    __shared__ unsigned short T[96][97];
    int t = threadIdx.x;
#pragma unroll
    for (int i = 0; i < 18; ++i) {
        int v = t + 256 * i;
        int r = v / 48, pp = v - r * 48;
        ushort2v u = *(const ushort2v*)(im + r * 96 + pp * 2);
        T[r][pp * 2] = u.x;
        T[r][pp * 2 + 1] = u.y;
    }
    __syncthreads();
#pragma unroll
    for (int i = 0; i < 18; ++i) {
        int v = t + 256 * i;
        int w = v / 48, hh = v - w * 48;
        ushort2v o = { T[hh * 2][w], T[hh * 2 + 1][w] };
        *(ushort2v*)(om + w * 96 + hh * 2) = o;
    }
}

// ---------------- scores + exp + row-partial-sums: grid (96, 2, g) ----------------
__global__ __launch_bounds__(256) void scores_kernel(
    const unsigned short* __restrict__ qT, const unsigned short* __restrict__ kT,
    const unsigned short* __restrict__ q, const unsigned short* __restrict__ k,
    unsigned short* __restrict__ attb, float* __restrict__ rsum0, float* __restrict__ rsum1)
{
    int s = blockIdx.x;
    int ori = blockIdx.y;
    size_t b = blockIdx.z;
    const unsigned short* qs = (ori ? q : qT) + b * (size_t)C8P;
    const unsigned short* ks = (ori ? k : kT) + b * (size_t)C8P;
    unsigned short* ab = attb + b * (size_t)ATTN;
    float* rs = (ori ? rsum1 : rsum0) + b * (size_t)PP;

    __shared__ float Qs[64][97];
    __shared__ float Ks[64][97];
    int t = threadIdx.x;
    for (int v = t; v < 64 * 12; v += 256) {
        int c = v / 12, gg = v - c * 12;
        size_t gi = (size_t)c * PP + (size_t)s * 96 + gg * 8;
        ushort8 uq = *(const ushort8*)(qs + gi);
        ushort8 uk = *(const ushort8*)(ks + gi);
#pragma unroll
        for (int kk = 0; kk < 8; ++kk) {
            Qs[c][gg * 8 + kk] = bf2f(uq[kk]);
            Ks[c][gg * 8 + kk] = bf2f(uk[kk]);
        }
    }
    __syncthreads();
    int tx = t & 15, ty = t >> 4;
    float acc[6][6] = {};
    for (int c = 0; c < 64; ++c) {
        float qf[6], kf[6];
#pragma unroll
        for (int i = 0; i < 6; ++i) { qf[i] = Qs[c][ty + 16 * i]; kf[i] = Ks[c][tx + 16 * i]; }
#pragma unroll
        for (int i = 0; i < 6; ++i)
#pragma unroll
            for (int j = 0; j < 6; ++j) acc[i][j] = fmaf(qf[i], kf[j], acc[i][j]);
    }
#pragma unroll
    for (int i = 0; i < 6; ++i) {
        int m = ty + 16 * i;
        size_t row = ori ? ((size_t)s * 96 + m) : ((size_t)m * 96 + s);
        unsigned short* rowp = ab + row * 192 + (ori ? 96 : 0);
        float part = 0.0f;
#pragma unroll
        for (int j = 0; j < 6; ++j) {
            int jj = tx + 16 * j;
            float e = (!ori && jj == m) ? 0.0f : __expf(acc[i][j] - 20.0f);
            part += e;
            rowp[jj] = f2bf(e);
        }
#pragma unroll
        for (int off = 1; off < 16; off <<= 1) part += __shfl_xor(part, off);
        if (tx == 0) rs[row] = part;
    }
}

// ---------------- MFMA apply on x: yT[p][c] unnormalized (norm folded into gemm_out) ----------------
// grid (96 s, 4 = path*2+ct, g), 512 thr = 8 waves (2 m x 4 n)
// Quad-j X staging: 4 rows per thread, ds_write_b64, same js = j^((cc&3)<<3) swizzle.
template<int ORI>
__global__ __launch_bounds__(512) void apply_mfma(
    const unsigned short* __restrict__ xT_e, const unsigned short* __restrict__ xT_q,
    unsigned short* __restrict__ yT_e, unsigned short* __restrict__ yT_q,
    const unsigned short* __restrict__ attb)
{
    int s = blockIdx.x;
    int path = blockIdx.y >> 1, ct = blockIdx.y & 1;
    int c0 = ct * 256;
    size_t b = blockIdx.z;
    const unsigned short* X = (path ? xT_q : xT_e) + b * (size_t)CP;
    unsigned short* Y = (path ? yT_q : yT_e) + b * (size_t)CP;
    const unsigned short* ab = attb + b * (size_t)ATTN;

    __shared__ __align__(16) unsigned short Att[96][104];
    __shared__ __align__(16) unsigned short Xs[256][104];   // [c][j] swizzled; reused as Wf[96][268]

    int tid = threadIdx.x;
    for (int v = tid; v < 96 * 12; v += 512) {
        int r = v / 12, gg = v - r * 12;
        size_t base = ORI ? ((size_t)(s * 96 + r) * 192 + 96) : ((size_t)(r * 96 + s) * 192);
        *(ushort8*)&Att[r][gg * 8] = *(const ushort8*)(ab + base + gg * 8);
    }
    // quad-j staging: 768 chunks (24 j-quads x 32 c-groups)
#pragma unroll
    for (int i = 0; i < 2; ++i) {
        int id = tid + 512 * i;
        if (id < 768) {
            int jq = id >> 5, cc = id & 31;
            int j = jq * 4;
            size_t stepP = ORI ? 1 : 96;
            size_t pj = ORI ? ((size_t)s * 96 + j) : ((size_t)j * 96 + s);
            const unsigned short* xp = X + pj * C_ + c0 + cc * 8;
            ushort8 u0 = *(const ushort8*)(xp);
            ushort8 u1 = *(const ushort8*)(xp + stepP * C_);
            ushort8 u2 = *(const ushort8*)(xp + 2 * stepP * C_);
            ushort8 u3 = *(const ushort8*)(xp + 3 * stepP * C_);
            int js = j ^ ((cc & 3) << 3);
#pragma unroll
            for (int e = 0; e < 8; ++e) {
                ushort4v o = { u0[e], u1[e], u2[e], u3[e] };
                *(ushort4v*)&Xs[cc * 8 + e][js] = o;
            }
        }
    }
    __syncthreads();

    int lane = tid & 63, wid = tid >> 6;
    int wm = wid >> 2, wn = wid & 3;
    int l15 = lane & 15, l4 = lane >> 4;
    f32x4 acc[3][4] = {};
#pragma unroll
    for (int k = 0; k < 3; ++k) {
        bf16x8 a[3], xx[4];
#pragma unroll
        for (int mi = 0; mi < 3; ++mi)
            a[mi] = *(const bf16x8*)&Att[wm * 48 + mi * 16 + l15][k * 32 + l4 * 8];
#pragma unroll
        for (int ni = 0; ni < 4; ++ni) {
            int row = wn * 64 + ni * 16 + l15;
            int gsw = (k * 4 + l4) ^ ((row >> 3) & 3);
            xx[ni] = *(const bf16x8*)&Xs[row][gsw * 8];
        }
#pragma unroll
        for (int mi = 0; mi < 3; ++mi)
#pragma unroll
            for (int ni = 0; ni < 4; ++ni)
                acc[mi][ni] = __builtin_amdgcn_mfma_f32_16x16x32_bf16(a[mi], xx[ni], acc[mi][ni], 0, 0, 0);
    }

    // ---- repack epilogue (coalesced ushort8 stores / RMW adds) ----
    unsigned short* Wf = &Xs[0][0];     // row stride 268 u16 (bank-clean)
    __syncthreads();                    // all Xs reads complete before overwrite
#pragma unroll
    for (int mi = 0; mi < 3; ++mi)
#pragma unroll
        for (int r = 0; r < 4; ++r) {
            int mrow = wm * 48 + mi * 16 + l4 * 4 + r;
#pragma unroll
            for (int ni = 0; ni < 4; ++ni)
                Wf[mrow * 268 + wn * 64 + ni * 16 + l15] = f2bf(acc[mi][ni][r]);
        }
    __syncthreads();
#pragma unroll
    for (int i = 0; i < 6; ++i) {
        int id = tid + 512 * i;
        int row = id >> 5, cg = id & 31;
        ushort4v w0 = *(const ushort4v*)&Wf[row * 268 + cg * 8];
        ushort4v w1 = *(const ushort4v*)&Wf[row * 268 + cg * 8 + 4];
        size_t p = ORI ? ((size_t)s * 96 + row) : ((size_t)row * 96 + s);
        unsigned short* yp = Y + p * C_ + c0 + cg * 8;
        if (ORI == 0) {
            ushort8 o = { w0[0], w0[1], w0[2], w0[3], w1[0], w1[1], w1[2], w1[3] };
            *(ushort8*)yp = o;
        } else {
            ushort8 yo = *(const ushort8*)yp;
            ushort8 o;
#pragma unroll
            for (int e = 0; e < 4; ++e) o[e] = f2bf(bf2f(yo[e]) + bf2f(w0[e]));
#pragma unroll
            for (int e = 0; e < 4; ++e) o[e + 4] = f2bf(bf2f(yo[e + 4]) + bf2f(w1[e]));
            *(ushort8*)yp = o;
        }
    }
}

// ---------------- final GEMM + fused epilogue: 512 thr, BK=64, swizzle, counted-vmcnt dbuf,
//                  x-prefetch in K-loop, XCD-bijective remap, per-column rinv normalize ----------------
__global__ __launch_bounds__(512) void gemm_out(
    const unsigned short* __restrict__ Wvb, const unsigned short* __restrict__ Wqvb,
    const unsigned short* __restrict__ yT_e, const unsigned short* __restrict__ yT_q,
    const float* __restrict__ bv, const float* __restrict__ bqv,
    const float* __restrict__ xe, const float* __restrict__ xq,
    const float* __restrict__ g1, const float* __restrict__ g2,
    const float* __restrict__ rsum0, const float* __restrict__ rsum1,
    float* __restrict__ o0, float* __restrict__ o1)
{
    // bijective XCD remap: 576 blocks/z; ot varies fastest within an XCD chunk
    int lin = blockIdx.x + 72 * blockIdx.y;
    int nid = (lin & 7) * 72 + (lin >> 3);
    int path = nid / 288;
    int rem = nid - path * 288;
    int ptile = rem >> 2, ot = rem & 3;

    const unsigned short* A = path ? Wqvb : Wvb;
    const float* bias = path ? bqv : bv;
    int p0 = ptile * 128;
    int o0r = ot * 128;
    size_t b = blockIdx.z;
    const unsigned short* Bb = (path ? yT_q : yT_e) + b * (size_t)CP;
    const float* xb = (path ? xq : xe) + b * (size_t)CP;
    float* ob = (path ? o1 : o0) + b * (size_t)CP;
    float gam = (path ? g2 : g1)[0];

    __shared__ __align__(16) unsigned short Asm[2][128 * 64];
    __shared__ __align__(16) unsigned short Bsm[2][128 * 64];

    int tid = threadIdx.x;             // 0..511, 8 waves
    int lane = tid & 63, wid = tid >> 6;
    int wr = wid >> 2, wc = wid & 3;   // 2 x 4 wave grid; wave tile 64 rows x 32 cols
    int l15 = lane & 15, l4 = lane >> 4;
    f32x4 acc[4][2] = {};
    float xv[4][2][4];                 // prefetched x residual (static-indexed)

#define GO_STAGE(KT, BUF)                                                                  \
    {                                                                                      \
        int k0s = (KT) * 64;                                                               \
        _Pragma("unroll")                                                                  \
        for (int i = 0; i < 2; ++i) {                                                      \
            int ch = tid + i * 512;                                                        \
            int row = ch >> 3, slot = ch & 7;                                              \
            int gs = slot ^ (row & 7);                                                     \
            gload16(A + (size_t)(o0r + row) * 512 + k0s + gs * 8, Asm[BUF] + ch * 8);      \
            gload16(Bb + (size_t)(p0 + row) * 512 + k0s + gs * 8, Bsm[BUF] + ch * 8);      \
        }                                                                                  \
    }

    GO_STAGE(0, 0);
    GO_STAGE(1, 1);

#pragma unroll
    for (int k = 0; k < 8; ++k) {
        int cur = k & 1;
        if (k == 0)      asm volatile("s_waitcnt vmcnt(4)" ::: "memory");
        else if (k < 7)  asm volatile("s_waitcnt vmcnt(8)" ::: "memory");
        else             asm volatile("s_waitcnt vmcnt(4)" ::: "memory");
        __builtin_amdgcn_s_barrier();
#pragma unroll
        for (int ks = 0; ks < 2; ++ks) {
            bf16x8 af[4], bfr[2];
#pragma unroll
            for (int m = 0; m < 4; ++m) {
                int row = wr * 64 + m * 16 + l15;
                int sl = (ks * 4 + l4) ^ (row & 7);
                af[m] = *(const bf16x8*)&Asm[cur][row * 64 + sl * 8];
            }
#pragma unroll
            for (int n = 0; n < 2; ++n) {
                int row = wc * 32 + n * 16 + l15;
                int sl = (ks * 4 + l4) ^ (row & 7);
                bfr[n] = *(const bf16x8*)&Bsm[cur][row * 64 + sl * 8];
            }
#pragma unroll
            for (int m = 0; m < 4; ++m)
#pragma unroll
                for (int n = 0; n < 2; ++n)
                    acc[m][n] = __builtin_amdgcn_mfma_f32_16x16x32_bf16(af[m], bfr[n], acc[m][n], 0, 0, 0);
        }
        asm volatile("" ::: "memory");
        __builtin_amdgcn_s_barrier();
        {   // x-prefetch chunk k: fragment (m = k>>1, n = k&1)
            int xm = k >> 1, xn = k & 1;
            int pcol = p0 + wc * 32 + xn * 16 + l15;
#pragma unroll
            for (int r = 0; r < 4; ++r) {
                int orow = o0r + wr * 64 + xm * 16 + l4 * 4 + r;
                xv[xm][xn][r] = xb[(size_t)orow * PP + pcol];
            }
        }
        if (k < 6) GO_STAGE(k + 2, cur);
    }
#undef GO_STAGE
    asm volatile("s_waitcnt vmcnt(0)" ::: "memory");

    float ri[2];
#pragma unroll
    for (int n = 0; n < 2; ++n) {
        int pcol = p0 + wc * 32 + n * 16 + l15;
        size_t pg = b * (size_t)PP + pcol;
        ri[n] = 1.0f / (rsum0[pg] + rsum1[pg]);
    }

#pragma unroll
    for (int m = 0; m < 4; ++m)
#pragma unroll
        for (int n = 0; n < 2; ++n) {
            int pcol = p0 + wc * 32 + n * 16 + l15;
#pragma unroll
            for (int r = 0; r < 4; ++r) {
                int orow = o0r + wr * 64 + m * 16 + l4 * 4 + r;
                size_t idx = (size_t)orow * PP + pcol;
                float val = acc[m][n][r] * ri[n] + bias[orow];
                ob[idx] = gam * (val + 2.0f) + xv[m][n][r];
            }
        }
}

extern "C" void kernel_launch(void* const* d_in, const int* in_sizes, int n_in,
                              void* d_out, int out_size, void* d_ws, size_t ws_size,
                              hipStream_t stream)
{
    const float* x_ex = (const float*)d_in[0];
    const float* x_q  = (const float*)d_in[1];
    const float* Wq   = (const float*)d_in[2];
    const float* bq   = (const float*)d_in[3];
    const float* Wk   = (const float*)d_in[4];
    const float* bk   = (const float*)d_in[5];
    const float* Wv   = (const float*)d_in[6];
    const float* bv   = (const float*)d_in[7];
    const float* Wqv  = (const float*)d_in[8];
    const float* bqv  = (const float*)d_in[9];
    const float* g1   = (const float*)d_in[10];
    const float* g2   = (const float*)d_in[11];
    float* out0 = (float*)d_out;
    float* out1 = out0 + (size_t)8 * CP;

    unsigned short* hp = (unsigned short*)d_ws;
    unsigned short* Wvb  = hp; hp += 262144;
    unsigned short* Wqvb = hp; hp += 262144;
    unsigned short* Wqb  = hp; hp += 32768;
    unsigned short* Wkb  = hp; hp += 32768;
    size_t head = (size_t)(hp - (unsigned short*)d_ws) * 2;

    size_t perB = 4ull * CP + (size_t)ATTN + 4ull * C8P + 4ull * PP;
    int g = 8;
    while (g > 1 && head + (size_t)g * perB * 2 > ws_size) g >>= 1;

    unsigned short* p = hp;
    unsigned short* xT_e = p; p += (size_t)g * CP;
    unsigned short* xT_q = p; p += (size_t)g * CP;
    unsigned short* yT_e = p; p += (size_t)g * CP;
    unsigned short* yT_q = p; p += (size_t)g * CP;
    unsigned short* attb = p; p += (size_t)g * ATTN;
    unsigned short* qb   = p; p += (size_t)g * C8P;
    unsigned short* kb   = p; p += (size_t)g * C8P;  // adjacent to qb
    unsigned short* qTb  = p; p += (size_t)g * C8P;
    unsigned short* kTb  = p; p += (size_t)g * C8P;  // adjacent to qTb
    float* rsum0 = (float*)p; p += (size_t)g * PP * 2;
    float* rsum1 = (float*)p; p += (size_t)g * PP * 2;

    cast_w<<<dim3(256, 4), 256, 0, stream>>>(Wv, Wqv, Wq, Wk, Wvb, Wqvb, Wqb, Wkb);

    for (int b0 = 0; b0 < 8; b0 += g) {
        const float* xe = x_ex + (size_t)b0 * CP;
        const float* xq = x_q  + (size_t)b0 * CP;
        float* o0 = out0 + (size_t)b0 * CP;
        float* o1 = out1 + (size_t)b0 * CP;

        cast_transpose_cp<<<dim3(144, 8, 2 * g), 256, 0, stream>>>(xq, xe, xT_q, xT_e);
        gemm_qk<<<dim3(72, 2, g), 256, 0, stream>>>(Wqb, Wkb, xT_q, xT_e, bq, bk, qb, kb);
        thw_b<<<dim3(2 * g * 64), 256, 0, stream>>>(qb, qTb);
        scores_kernel<<<dim3(96, 2, g), 256, 0, stream>>>(qTb, kTb, qb, kb, attb, rsum0, rsum1);
        apply_mfma<0><<<dim3(96, 4, g), 512, 0, stream>>>(xT_e, xT_q, yT_e, yT_q, attb);
        apply_mfma<1><<<dim3(96, 4, g), 512, 0, stream>>>(xT_e, xT_q, yT_e, yT_q, attb);
        gemm_out<<<dim3(72, 8, g), 512, 0, stream>>>(Wvb, Wqvb, yT_e, yT_q, bv, bqv,
                                                     xe, xq, g1, g2, rsum0, rsum1, o0, o1);
    }
}

// Round 18
// 520.116 us; speedup vs baseline: 1.1365x; 1.0042x over previous
//
#include <hip/hip_runtime.h>
#include <math.h>

#define C_   512
#define C8_  64
#define HH   96
#define WW   96
#define PP   9216            // HH*WW
#define CP   4718592         // C_*PP
#define C8P  589824          // C8_*PP
#define ATTN 1769472         // PP*192

typedef __attribute__((ext_vector_type(4))) float f32x4;
typedef __attribute__((ext_vector_type(8))) __bf16 bf16x8;
typedef __attribute__((ext_vector_type(8))) unsigned short ushort8;
typedef __attribute__((ext_vector_type(4))) unsigned short ushort4v;
typedef __attribute__((ext_vector_type(2))) unsigned short ushort2v;
typedef __attribute__((ext_vector_type(2))) float float2v;

__device__ __forceinline__ float bf2f(unsigned short u) {
    union { unsigned u; float f; } x; x.u = ((unsigned)u) << 16; return x.f;
}
__device__ __forceinline__ unsigned short f2bf(float f) {
    union { float f; unsigned u; } x; x.f = f;
    unsigned r = x.u + 0x7fffu + ((x.u >> 16) & 1u);
    return (unsigned short)(r >> 16);
}
__device__ __forceinline__ void gload16(const void* g, void* l) {
    __builtin_amdgcn_global_load_lds(
        (const __attribute__((address_space(1))) unsigned int*)g,
        (__attribute__((address_space(3))) unsigned int*)l, 16, 0, 0);
}

// ---------------- all 4 weight casts in one dispatch ----------------
__global__ __launch_bounds__(256) void cast_w(
    const float* __restrict__ Wv, const float* __restrict__ Wqv,
    const float* __restrict__ Wq, const float* __restrict__ Wk,
    unsigned short* __restrict__ oV, unsigned short* __restrict__ oQV,
    unsigned short* __restrict__ oQ, unsigned short* __restrict__ oK)
{
    int y = blockIdx.y;
    int n = (y < 2) ? 262144 : 32768;
    const float* s = (y == 0) ? Wv : (y == 1) ? Wqv : (y == 2) ? Wq : Wk;
    unsigned short* d = (y == 0) ? oV : (y == 1) ? oQV : (y == 2) ? oQ : oK;
    int i = (blockIdx.x * 256 + threadIdx.x) * 4;
    if (i < n) {
        float4 v = *(const float4*)(s + i);
        ushort4v o = { f2bf(v.x), f2bf(v.y), f2bf(v.z), f2bf(v.w) };
        *(ushort4v*)(d + i) = o;
    }
}

// ---------------- x fp32 [C][P] -> xT bf16 [P][C], both tensors ----------------
__global__ __launch_bounds__(256) void cast_transpose_cp(
    const float* __restrict__ xq, const float* __restrict__ xe,
    unsigned short* __restrict__ xTq, unsigned short* __restrict__ xTe)
{
    int zz = blockIdx.z;
    int which = zz & 1;
    size_t b = zz >> 1;
    const float* xb = (which ? xe : xq) + b * (size_t)CP;
    unsigned short* xTb = (which ? xTe : xTq) + b * (size_t)CP;
    int p0 = blockIdx.x * 64, c0 = blockIdx.y * 64;

    __shared__ unsigned short T[64][65];
    int t = threadIdx.x;
    int pp = t & 31, cg = t >> 5;
#pragma unroll
    for (int i = 0; i < 8; ++i) {
        int c = cg + 8 * i;
        float2v v = *(const float2v*)(xb + (size_t)(c0 + c) * PP + p0 + pp * 2);
        T[c][pp * 2] = f2bf(v.x);
        T[c][pp * 2 + 1] = f2bf(v.y);
    }
    __syncthreads();
    int cp = t & 31;
#pragma unroll
    for (int i = 0; i < 8; ++i) {
        int e = t + 256 * i;
        int p = e >> 5;
        ushort2v o = { T[cp * 2][p], T[cp * 2 + 1][p] };
        *(ushort2v*)(xTb + (size_t)(p0 + p) * C_ + c0 + cp * 2) = o;
    }
}

// ---------------- MFMA GEMM q & k (BM=64, bf16 out), counted-vmcnt 2-phase ----------------
__global__ __launch_bounds__(256) void gemm_qk(
    const unsigned short* __restrict__ Wqb, const unsigned short* __restrict__ Wkb,
    const unsigned short* __restrict__ xTq, const unsigned short* __restrict__ xTe,
    const float* __restrict__ bq, const float* __restrict__ bk,
    unsigned short* __restrict__ qout, unsigned short* __restrict__ kout)
{
    int sel = blockIdx.y;
    const unsigned short* A = sel ? Wkb : Wqb;
    const float* bias = sel ? bk : bq;
    int p0 = blockIdx.x * 128;
    size_t b = blockIdx.z;
    const unsigned short* Bb = (sel ? xTe : xTq) + b * (size_t)CP;
    unsigned short* outb = (sel ? kout : qout) + b * (size_t)C8P;

    __shared__ __align__(16) unsigned short Asm[2][64 * 32];
    __shared__ __align__(16) unsigned short Bsm[2][128 * 32];

    int tid = threadIdx.x;
    int lane = tid & 63, wid = tid >> 6;
    int wr = wid >> 1, wc = wid & 1;
    int l15 = lane & 15, l4 = lane >> 4;
    f32x4 acc[2][4] = {};

#define QK_STAGE(KT, BUF)                                                              \
    {                                                                                  \
        int k0s = (KT) * 32;                                                           \
        int c = tid;                                                                   \
        gload16(A + (size_t)(c >> 2) * 512 + k0s + (c & 3) * 8, Asm[BUF] + c * 8);     \
        gload16(Bb + (size_t)(p0 + (c >> 2)) * 512 + k0s + (c & 3) * 8, Bsm[BUF] + c * 8); \
        int cb = tid + 256;                                                            \
        gload16(Bb + (size_t)(p0 + (cb >> 2)) * 512 + k0s + (cb & 3) * 8, Bsm[BUF] + cb * 8); \
    }

    QK_STAGE(0, 0);
    QK_STAGE(1, 1);

#pragma unroll
    for (int k = 0; k < 16; ++k) {
        int cur = k & 1;
        if (k < 15) asm volatile("s_waitcnt vmcnt(3)" ::: "memory");
        else        asm volatile("s_waitcnt vmcnt(0)" ::: "memory");
        __builtin_amdgcn_s_barrier();
        bf16x8 af[2], bfr[4];
#pragma unroll
        for (int m = 0; m < 2; ++m)
            af[m] = *(const bf16x8*)&Asm[cur][(wr * 32 + m * 16 + l15) * 32 + l4 * 8];
#pragma unroll
        for (int n = 0; n < 4; ++n)
            bfr[n] = *(const bf16x8*)&Bsm[cur][(wc * 64 + n * 16 + l15) * 32 + l4 * 8];
#pragma unroll
        for (int m = 0; m < 2; ++m)
#pragma unroll
            for (int n = 0; n < 4; ++n)
                acc[m][n] = __builtin_amdgcn_mfma_f32_16x16x32_bf16(af[m], bfr[n], acc[m][n], 0, 0, 0);
        asm volatile("" ::: "memory");
        __builtin_amdgcn_s_barrier();
        if (k < 14) QK_STAGE(k + 2, cur);
    }
#undef QK_STAGE

#pragma unroll
    for (int m = 0; m < 2; ++m)
#pragma unroll
        for (int n = 0; n < 4; ++n) {
            int pcol = p0 + wc * 64 + n * 16 + l15;
#pragma unroll
            for (int r = 0; r < 4; ++r) {
                int orow = wr * 32 + m * 16 + l4 * 4 + r;
                outb[(size_t)orow * PP + pcol] = f2bf(acc[m][n][r] + bias[orow]);
            }
        }
}

// ---------------- bf16 96x96 spatial transpose (q,k only) ----------------
__global__ __launch_bounds__(256) void thw_b(
    const unsigned short* __restrict__ in, unsigned short* __restrict__ out)
{
    size_t m = blockIdx.x;
    const unsigned short* im = in + m * (size_t)PP;
    unsigned short* om = out + m * (size_t)PP;
    __shared__ unsigned short T[96][97];
    int t = threadIdx.x;
#pragma unroll
    for (int i = 0; i < 18; ++i) {
        int v = t + 256 * i;
        int r = v / 48, pp = v - r * 48;
        ushort2v u = *(const ushort2v*)(im + r * 96 + pp * 2);
        T[r][pp * 2] = u.x;
        T[r][pp * 2 + 1] = u.y;
    }
    __syncthreads();
#pragma unroll
    for (int i = 0; i < 18; ++i) {
        int v = t + 256 * i;
        int w = v / 48, hh = v - w * 48;
        ushort2v o = { T[hh * 2][w], T[hh * 2 + 1][w] };
        *(ushort2v*)(om + w * 96 + hh * 2) = o;
    }
}

// ---------------- scores + exp + row-partial-sums: grid (96, 2, g) ----------------
__global__ __launch_bounds__(256) void scores_kernel(
    const unsigned short* __restrict__ qT, const unsigned short* __restrict__ kT,
    const unsigned short* __restrict__ q, const unsigned short* __restrict__ k,
    unsigned short* __restrict__ attb, float* __restrict__ rsum0, float* __restrict__ rsum1)
{
    int s = blockIdx.x;
    int ori = blockIdx.y;
    size_t b = blockIdx.z;
    const unsigned short* qs = (ori ? q : qT) + b * (size_t)C8P;
    const unsigned short* ks = (ori ? k : kT) + b * (size_t)C8P;
    unsigned short* ab = attb + b * (size_t)ATTN;
    float* rs = (ori ? rsum1 : rsum0) + b * (size_t)PP;

    __shared__ float Qs[64][97];
    __shared__ float Ks[64][97];
    int t = threadIdx.x;
    for (int v = t; v < 64 * 12; v += 256) {
        int c = v / 12, gg = v - c * 12;
        size_t gi = (size_t)c * PP + (size_t)s * 96 + gg * 8;
        ushort8 uq = *(const ushort8*)(qs + gi);
        ushort8 uk = *(const ushort8*)(ks + gi);
#pragma unroll
        for (int kk = 0; kk < 8; ++kk) {
            Qs[c][gg * 8 + kk] = bf2f(uq[kk]);
            Ks[c][gg * 8 + kk] = bf2f(uk[kk]);
        }
    }
    __syncthreads();
    int tx = t & 15, ty = t >> 4;
    float acc[6][6] = {};
    for (int c = 0; c < 64; ++c) {
        float qf[6], kf[6];
#pragma unroll
        for (int i = 0; i < 6; ++i) { qf[i] = Qs[c][ty + 16 * i]; kf[i] = Ks[c][tx + 16 * i]; }
#pragma unroll
        for (int i = 0; i < 6; ++i)
#pragma unroll
            for (int j = 0; j < 6; ++j) acc[i][j] = fmaf(qf[i], kf[j], acc[i][j]);
    }
#pragma unroll
    for (int i = 0; i < 6; ++i) {
        int m = ty + 16 * i;
        size_t row = ori ? ((size_t)s * 96 + m) : ((size_t)m * 96 + s);
        unsigned short* rowp = ab + row * 192 + (ori ? 96 : 0);
        float part = 0.0f;
#pragma unroll
        for (int j = 0; j < 6; ++j) {
            int jj = tx + 16 * j;
            float e = (!ori && jj == m) ? 0.0f : __expf(acc[i][j] - 20.0f);
            part += e;
            rowp[jj] = f2bf(e);
        }
#pragma unroll
        for (int off = 1; off < 16; off <<= 1) part += __shfl_xor(part, off);
        if (tx == 0) rs[row] = part;
    }
}

// ---------------- MFMA apply on x: yT[p][c] unnormalized (norm folded into gemm_out) ----------------
// grid (96 s, 4 = path*2+ct, g), 512 thr = 8 waves (2 m x 4 n)
// ORI=1 prefetches Y RMW operands before the MFMA phase (latency hidden under compute).
template<int ORI>
__global__ __launch_bounds__(512) void apply_mfma(
    const unsigned short* __restrict__ xT_e, const unsigned short* __restrict__ xT_q,
    unsigned short* __restrict__ yT_e, unsigned short* __restrict__ yT_q,
    const unsigned short* __restrict__ attb)
{
    int s = blockIdx.x;
    int path = blockIdx.y >> 1, ct = blockIdx.y & 1;
    int c0 = ct * 256;
    size_t b = blockIdx.z;
    const unsigned short* X = (path ? xT_q : xT_e) + b * (size_t)CP;
    unsigned short* Y = (path ? yT_q : yT_e) + b * (size_t)CP;
    const unsigned short* ab = attb + b * (size_t)ATTN;

    __shared__ __align__(16) unsigned short Att[96][104];
    __shared__ __align__(16) unsigned short Xs[256][104];   // [c][j] swizzled; reused as Wf[96][268]

    int tid = threadIdx.x;
    for (int v = tid; v < 96 * 12; v += 512) {
        int r = v / 12, gg = v - r * 12;
        size_t base = ORI ? ((size_t)(s * 96 + r) * 192 + 96) : ((size_t)(r * 96 + s) * 192);
        *(ushort8*)&Att[r][gg * 8] = *(const ushort8*)(ab + base + gg * 8);
    }
    // quad-j staging: 768 chunks (24 j-quads x 32 c-groups)
#pragma unroll
    for (int i = 0; i < 2; ++i) {
        int id = tid + 512 * i;
        if (id < 768) {
            int jq = id >> 5, cc = id & 31;
            int j = jq * 4;
            size_t stepP = ORI ? 1 : 96;
            size_t pj = ORI ? ((size_t)s * 96 + j) : ((size_t)j * 96 + s);
            const unsigned short* xp = X + pj * C_ + c0 + cc * 8;
            ushort8 u0 = *(const ushort8*)(xp);
            ushort8 u1 = *(const ushort8*)(xp + stepP * C_);
            ushort8 u2 = *(const ushort8*)(xp + 2 * stepP * C_);
            ushort8 u3 = *(const ushort8*)(xp + 3 * stepP * C_);
            int js = j ^ ((cc & 3) << 3);
#pragma unroll
            for (int e = 0; e < 8; ++e) {
                ushort4v o = { u0[e], u1[e], u2[e], u3[e] };
                *(ushort4v*)&Xs[cc * 8 + e][js] = o;
            }
        }
    }

    // ORI=1: prefetch Y RMW operands now; latency hides under the MFMA phase
    ushort8 yo[6];
    if (ORI) {
#pragma unroll
        for (int i = 0; i < 6; ++i) {
            int id = tid + 512 * i;
            int row = id >> 5, cg = id & 31;
            size_t p = (size_t)s * 96 + row;
            yo[i] = *(const ushort8*)(Y + p * C_ + c0 + cg * 8);
        }
    }
    __syncthreads();

    int lane = tid & 63, wid = tid >> 6;
    int wm = wid >> 2, wn = wid & 3;
    int l15 = lane & 15, l4 = lane >> 4;
    f32x4 acc[3][4] = {};
#pragma unroll
    for (int k = 0; k < 3; ++k) {
        bf16x8 a[3], xx[4];
#pragma unroll
        for (int mi = 0; mi < 3; ++mi)
            a[mi] = *(const bf16x8*)&Att[wm * 48 + mi * 16 + l15][k * 32 + l4 * 8];
#pragma unroll
        for (int ni = 0; ni < 4; ++ni) {
            int row = wn * 64 + ni * 16 + l15;
            int gsw = (k * 4 + l4) ^ ((row >> 3) & 3);
            xx[ni] = *(const bf16x8*)&Xs[row][gsw * 8];
        }
#pragma unroll
        for (int mi = 0; mi < 3; ++mi)
#pragma unroll
            for (int ni = 0; ni < 4; ++ni)
                acc[mi][ni] = __builtin_amdgcn_mfma_f32_16x16x32_bf16(a[mi], xx[ni], acc[mi][ni], 0, 0, 0);
    }

    // ---- repack epilogue (coalesced ushort8 stores / RMW adds) ----
    unsigned short* Wf = &Xs[0][0];     // row stride 268 u16 (bank-clean)
    __syncthreads();                    // all Xs reads complete before overwrite
#pragma unroll
    for (int mi = 0; mi < 3; ++mi)
#pragma unroll
        for (int r = 0; r < 4; ++r) {
            int mrow = wm * 48 + mi * 16 + l4 * 4 + r;
#pragma unroll
            for (int ni = 0; ni < 4; ++ni)
                Wf[mrow * 268 + wn * 64 + ni * 16 + l15] = f2bf(acc[mi][ni][r]);
        }
    __syncthreads();
#pragma unroll
    for (int i = 0; i < 6; ++i) {
        int id = tid + 512 * i;
        int row = id >> 5, cg = id & 31;
        ushort4v w0 = *(const ushort4v*)&Wf[row * 268 + cg * 8];
        ushort4v w1 = *(const ushort4v*)&Wf[row * 268 + cg * 8 + 4];
        size_t p = ORI ? ((size_t)s * 96 + row) : ((size_t)row * 96 + s);
        unsigned short* yp = Y + p * C_ + c0 + cg * 8;
        if (ORI == 0) {
            ushort8 o = { w0[0], w0[1], w0[2], w0[3], w1[0], w1[1], w1[2], w1[3] };
            *(ushort8*)yp = o;
        } else {
            ushort8 o;
#pragma unroll
            for (int e = 0; e < 4; ++e) o[e] = f2bf(bf2f(yo[i][e]) + bf2f(w0[e]));
#pragma unroll
            for (int e = 0; e < 4; ++e) o[e + 4] = f2bf(bf2f(yo[i][e + 4]) + bf2f(w1[e]));
            *(ushort8*)yp = o;
        }
    }
}

// ---------------- final GEMM + fused epilogue: 512 thr, BK=64, swizzle, counted-vmcnt dbuf,
//                  x-prefetch in K-loop, XCD-bijective remap, rinv loaded in prologue ----------------
__global__ __launch_bounds__(512) void gemm_out(
    const unsigned short* __restrict__ Wvb, const unsigned short* __restrict__ Wqvb,
    const unsigned short* __restrict__ yT_e, const unsigned short* __restrict__ yT_q,
    const float* __restrict__ bv, const float* __restrict__ bqv,
    const float* __restrict__ xe, const float* __restrict__ xq,
    const float* __restrict__ g1, const float* __restrict__ g2,
    const float* __restrict__ rsum0, const float* __restrict__ rsum1,
    float* __restrict__ o0, float* __restrict__ o1)
{
    // bijective XCD remap: 576 blocks/z; ot varies fastest within an XCD chunk
    int lin = blockIdx.x + 72 * blockIdx.y;
    int nid = (lin & 7) * 72 + (lin >> 3);
    int path = nid / 288;
    int rem = nid - path * 288;
    int ptile = rem >> 2, ot = rem & 3;

    const unsigned short* A = path ? Wqvb : Wvb;
    const float* bias = path ? bqv : bv;
    int p0 = ptile * 128;
    int o0r = ot * 128;
    size_t b = blockIdx.z;
    const unsigned short* Bb = (path ? yT_q : yT_e) + b * (size_t)CP;
    const float* xb = (path ? xq : xe) + b * (size_t)CP;
    float* ob = (path ? o1 : o0) + b * (size_t)CP;
    float gam = (path ? g2 : g1)[0];

    __shared__ __align__(16) unsigned short Asm[2][128 * 64];
    __shared__ __align__(16) unsigned short Bsm[2][128 * 64];

    int tid = threadIdx.x;             // 0..511, 8 waves
    int lane = tid & 63, wid = tid >> 6;
    int wr = wid >> 2, wc = wid & 3;   // 2 x 4 wave grid; wave tile 64 rows x 32 cols
    int l15 = lane & 15, l4 = lane >> 4;
    f32x4 acc[4][2] = {};
    float xv[4][2][4];                 // prefetched x residual (static-indexed)

#define GO_STAGE(KT, BUF)                                                                  \
    {                                                                                      \
        int k0s = (KT) * 64;                                                               \
        _Pragma("unroll")                                                                  \
        for (int i = 0; i < 2; ++i) {                                                      \
            int ch = tid + i * 512;                                                        \
            int row = ch >> 3, slot = ch & 7;                                              \
            int gs = slot ^ (row & 7);                                                     \
            gload16(A + (size_t)(o0r + row) * 512 + k0s + gs * 8, Asm[BUF] + ch * 8);      \
            gload16(Bb + (size_t)(p0 + row) * 512 + k0s + gs * 8, Bsm[BUF] + ch * 8);      \
        }                                                                                  \
    }

    GO_STAGE(0, 0);
    GO_STAGE(1, 1);

    // rinv operand loads issued in prologue; consumed only after final vmcnt(0).
    // Safe with the R14 wait ladder: at k==0, vmcnt(4) forces 8 of the 12 outstanding
    // ops complete, and s0's 4 can never be among the 4 newest (s1+rsum issued later).
    float rsa[2], rsb[2];
#pragma unroll
    for (int n = 0; n < 2; ++n) {
        int pcol = p0 + wc * 32 + n * 16 + l15;
        size_t pg = b * (size_t)PP + pcol;
        rsa[n] = rsum0[pg];
        rsb[n] = rsum1[pg];
    }

#pragma unroll
    for (int k = 0; k < 8; ++k) {
        int cur = k & 1;
        if (k == 0)      asm volatile("s_waitcnt vmcnt(4)" ::: "memory");
        else if (k < 7)  asm volatile("s_waitcnt vmcnt(8)" ::: "memory");
        else             asm volatile("s_waitcnt vmcnt(4)" ::: "memory");
        __builtin_amdgcn_s_barrier();
#pragma unroll
        for (int ks = 0; ks < 2; ++ks) {
            bf16x8 af[4], bfr[2];
#pragma unroll
            for (int m = 0; m < 4; ++m) {
                int row = wr * 64 + m * 16 + l15;
                int sl = (ks * 4 + l4) ^ (row & 7);
                af[m] = *(const bf16x8*)&Asm[cur][row * 64 + sl * 8];
            }
#pragma unroll
            for (int n = 0; n < 2; ++n) {
                int row = wc * 32 + n * 16 + l15;
                int sl = (ks * 4 + l4) ^ (row & 7);
                bfr[n] = *(const bf16x8*)&Bsm[cur][row * 64 + sl * 8];
            }
#pragma unroll
            for (int m = 0; m < 4; ++m)
#pragma unroll
                for (int n = 0; n < 2; ++n)
                    acc[m][n] = __builtin_amdgcn_mfma_f32_16x16x32_bf16(af[m], bfr[n], acc[m][n], 0, 0, 0);
        }
        asm volatile("" ::: "memory");
        __builtin_amdgcn_s_barrier();
        {   // x-prefetch chunk k: fragment (m = k>>1, n = k&1)
            int xm = k >> 1, xn = k & 1;
            int pcol = p0 + wc * 32 + xn * 16 + l15;
#pragma unroll
            for (int r = 0; r < 4; ++r) {
                int orow = o0r + wr * 64 + xm * 16 + l4 * 4 + r;
                xv[xm][xn][r] = xb[(size_t)orow * PP + pcol];
            }
        }
        if (k < 6) GO_STAGE(k + 2, cur);
    }
#undef GO_STAGE
    asm volatile("s_waitcnt vmcnt(0)" ::: "memory");

    float ri[2];
#pragma unroll
    for (int n = 0; n < 2; ++n) ri[n] = 1.0f / (rsa[n] + rsb[n]);

#pragma unroll
    for (int m = 0; m < 4; ++m)
#pragma unroll
        for (int n = 0; n < 2; ++n) {
            int pcol = p0 + wc * 32 + n * 16 + l15;
#pragma unroll
            for (int r = 0; r < 4; ++r) {
                int orow = o0r + wr * 64 + m * 16 + l4 * 4 + r;
                size_t idx = (size_t)orow * PP + pcol;
                float val = acc[m][n][r] * ri[n] + bias[orow];
                ob[idx] = gam * (val + 2.0f) + xv[m][n][r];
            }
        }
}

extern "C" void kernel_launch(void* const* d_in, const int* in_sizes, int n_in,
                              void* d_out, int out_size, void* d_ws, size_t ws_size,
                              hipStream_t stream)
{
    const float* x_ex = (const float*)d_in[0];
    const float* x_q  = (const float*)d_in[1];
    const float* Wq   = (const float*)d_in[2];
    const float* bq   = (const float*)d_in[3];
    const float* Wk   = (const float*)d_in[4];
    const float* bk   = (const float*)d_in[5];
    const float* Wv   = (const float*)d_in[6];
    const float* bv   = (const float*)d_in[7];
    const float* Wqv  = (const float*)d_in[8];
    const float* bqv  = (const float*)d_in[9];
    const float* g1   = (const float*)d_in[10];
    const float* g2   = (const float*)d_in[11];
    float* out0 = (float*)d_out;
    float* out1 = out0 + (size_t)8 * CP;

    unsigned short* hp = (unsigned short*)d_ws;
    unsigned short* Wvb  = hp; hp += 262144;
    unsigned short* Wqvb = hp; hp += 262144;
    unsigned short* Wqb  = hp; hp += 32768;
    unsigned short* Wkb  = hp; hp += 32768;
    size_t head = (size_t)(hp - (unsigned short*)d_ws) * 2;

    size_t perB = 4ull * CP + (size_t)ATTN + 4ull * C8P + 4ull * PP;
    int g = 8;
    while (g > 1 && head + (size_t)g * perB * 2 > ws_size) g >>= 1;

    unsigned short* p = hp;
    unsigned short* xT_e = p; p += (size_t)g * CP;
    unsigned short* xT_q = p; p += (size_t)g * CP;
    unsigned short* yT_e = p; p += (size_t)g * CP;
    unsigned short* yT_q = p; p += (size_t)g * CP;
    unsigned short* attb = p; p += (size_t)g * ATTN;
    unsigned short* qb   = p; p += (size_t)g * C8P;
    unsigned short* kb   = p; p += (size_t)g * C8P;  // adjacent to qb
    unsigned short* qTb  = p; p += (size_t)g * C8P;
    unsigned short* kTb  = p; p += (size_t)g * C8P;  // adjacent to qTb
    float* rsum0 = (float*)p; p += (size_t)g * PP * 2;
    float* rsum1 = (float*)p; p += (size_t)g * PP * 2;

    cast_w<<<dim3(256, 4), 256, 0, stream>>>(Wv, Wqv, Wq, Wk, Wvb, Wqvb, Wqb, Wkb);

    for (int b0 = 0; b0 < 8; b0 += g) {
        const float* xe = x_ex + (size_t)b0 * CP;
        const float* xq = x_q  + (size_t)b0 * CP;
        float* o0 = out0 + (size_t)b0 * CP;
        float* o1 = out1 + (size_t)b0 * CP;

        cast_transpose_cp<<<dim3(144, 8, 2 * g), 256, 0, stream>>>(xq, xe, xT_q, xT_e);
        gemm_qk<<<dim3(72, 2, g), 256, 0, stream>>>(Wqb, Wkb, xT_q, xT_e, bq, bk, qb, kb);
        thw_b<<<dim3(2 * g * 64), 256, 0, stream>>>(qb, qTb);
        scores_kernel<<<dim3(96, 2, g), 256, 0, stream>>>(qTb, kTb, qb, kb, attb, rsum0, rsum1);
        apply_mfma<0><<<dim3(96, 4, g), 512, 0, stream>>>(xT_e, xT_q, yT_e, yT_q, attb);
        apply_mfma<1><<<dim3(96, 4, g), 512, 0, stream>>>(xT_e, xT_q, yT_e, yT_q, attb);
        gemm_out<<<dim3(72, 8, g), 512, 0, stream>>>(Wvb, Wqvb, yT_e, yT_q, bv, bqv,
                                                     xe, xq, g1, g2, rsum0, rsum1, o0, o1);
    }
}

// Round 19
// 518.854 us; speedup vs baseline: 1.1392x; 1.0024x over previous
//
#include <hip/hip_runtime.h>
#include <math.h>

#define C_   512
#define C8_  64
#define HH   96
#define WW   96
#define PP   9216            // HH*WW
#define CP   4718592         // C_*PP
#define C8P  589824          // C8_*PP
#define ATTN 1769472         // PP*192

typedef __attribute__((ext_vector_type(4))) float f32x4;
typedef __attribute__((ext_vector_type(8))) __bf16 bf16x8;
typedef __attribute__((ext_vector_type(8))) unsigned short ushort8;
typedef __attribute__((ext_vector_type(4))) unsigned short ushort4v;
typedef __attribute__((ext_vector_type(2))) unsigned short ushort2v;
typedef __attribute__((ext_vector_type(2))) float float2v;

__device__ __forceinline__ float bf2f(unsigned short u) {
    union { unsigned u; float f; } x; x.u = ((unsigned)u) << 16; return x.f;
}
__device__ __forceinline__ unsigned short f2bf(float f) {
    union { float f; unsigned u; } x; x.f = f;
    unsigned r = x.u + 0x7fffu + ((x.u >> 16) & 1u);
    return (unsigned short)(r >> 16);
}
__device__ __forceinline__ void gload16(const void* g, void* l) {
    __builtin_amdgcn_global_load_lds(
        (const __attribute__((address_space(1))) unsigned int*)g,
        (__attribute__((address_space(3))) unsigned int*)l, 16, 0, 0);
}

// ---------------- all 4 weight casts in one dispatch ----------------
__global__ __launch_bounds__(256) void cast_w(
    const float* __restrict__ Wv, const float* __restrict__ Wqv,
    const float* __restrict__ Wq, const float* __restrict__ Wk,
    unsigned short* __restrict__ oV, unsigned short* __restrict__ oQV,
    unsigned short* __restrict__ oQ, unsigned short* __restrict__ oK)
{
    int y = blockIdx.y;
    int n = (y < 2) ? 262144 : 32768;
    const float* s = (y == 0) ? Wv : (y == 1) ? Wqv : (y == 2) ? Wq : Wk;
    unsigned short* d = (y == 0) ? oV : (y == 1) ? oQV : (y == 2) ? oQ : oK;
    int i = (blockIdx.x * 256 + threadIdx.x) * 4;
    if (i < n) {
        float4 v = *(const float4*)(s + i);
        ushort4v o = { f2bf(v.x), f2bf(v.y), f2bf(v.z), f2bf(v.w) };
        *(ushort4v*)(d + i) = o;
    }
}

// ---------------- x fp32 [C][P] -> xT bf16 [P][C], both tensors ----------------
__global__ __launch_bounds__(256) void cast_transpose_cp(
    const float* __restrict__ xq, const float* __restrict__ xe,
    unsigned short* __restrict__ xTq, unsigned short* __restrict__ xTe)
{
    int zz = blockIdx.z;
    int which = zz & 1;
    size_t b = zz >> 1;
    const float* xb = (which ? xe : xq) + b * (size_t)CP;
    unsigned short* xTb = (which ? xTe : xTq) + b * (size_t)CP;
    int p0 = blockIdx.x * 64, c0 = blockIdx.y * 64;

    __shared__ unsigned short T[64][65];
    int t = threadIdx.x;
    int pp = t & 31, cg = t >> 5;
#pragma unroll
    for (int i = 0; i < 8; ++i) {
        int c = cg + 8 * i;
        float2v v = *(const float2v*)(xb + (size_t)(c0 + c) * PP + p0 + pp * 2);
        T[c][pp * 2] = f2bf(v.x);
        T[c][pp * 2 + 1] = f2bf(v.y);
    }
    __syncthreads();
    int cp = t & 31;
#pragma unroll
    for (int i = 0; i < 8; ++i) {
        int e = t + 256 * i;
        int p = e >> 5;
        ushort2v o = { T[cp * 2][p], T[cp * 2 + 1][p] };
        *(ushort2v*)(xTb + (size_t)(p0 + p) * C_ + c0 + cp * 2) = o;
    }
}

// ---------------- MFMA GEMM q & k (BM=64, bf16 out), counted-vmcnt 2-phase ----------------
__global__ __launch_bounds__(256) void gemm_qk(
    const unsigned short* __restrict__ Wqb, const unsigned short* __restrict__ Wkb,
    const unsigned short* __restrict__ xTq, const unsigned short* __restrict__ xTe,
    const float* __restrict__ bq, const float* __restrict__ bk,
    unsigned short* __restrict__ qout, unsigned short* __restrict__ kout)
{
    int sel = blockIdx.y;
    const unsigned short* A = sel ? Wkb : Wqb;
    const float* bias = sel ? bk : bq;
    int p0 = blockIdx.x * 128;
    size_t b = blockIdx.z;
    const unsigned short* Bb = (sel ? xTe : xTq) + b * (size_t)CP;
    unsigned short* outb = (sel ? kout : qout) + b * (size_t)C8P;

    __shared__ __align__(16) unsigned short Asm[2][64 * 32];
    __shared__ __align__(16) unsigned short Bsm[2][128 * 32];

    int tid = threadIdx.x;
    int lane = tid & 63, wid = tid >> 6;
    int wr = wid >> 1, wc = wid & 1;
    int l15 = lane & 15, l4 = lane >> 4;
    f32x4 acc[2][4] = {};

#define QK_STAGE(KT, BUF)                                                              \
    {                                                                                  \
        int k0s = (KT) * 32;                                                           \
        int c = tid;                                                                   \
        gload16(A + (size_t)(c >> 2) * 512 + k0s + (c & 3) * 8, Asm[BUF] + c * 8);     \
        gload16(Bb + (size_t)(p0 + (c >> 2)) * 512 + k0s + (c & 3) * 8, Bsm[BUF] + c * 8); \
        int cb = tid + 256;                                                            \
        gload16(Bb + (size_t)(p0 + (cb >> 2)) * 512 + k0s + (cb & 3) * 8, Bsm[BUF] + cb * 8); \
    }

    QK_STAGE(0, 0);
    QK_STAGE(1, 1);

#pragma unroll
    for (int k = 0; k < 16; ++k) {
        int cur = k & 1;
        if (k < 15) asm volatile("s_waitcnt vmcnt(3)" ::: "memory");
        else        asm volatile("s_waitcnt vmcnt(0)" ::: "memory");
        __builtin_amdgcn_s_barrier();
        bf16x8 af[2], bfr[4];
#pragma unroll
        for (int m = 0; m < 2; ++m)
            af[m] = *(const bf16x8*)&Asm[cur][(wr * 32 + m * 16 + l15) * 32 + l4 * 8];
#pragma unroll
        for (int n = 0; n < 4; ++n)
            bfr[n] = *(const bf16x8*)&Bsm[cur][(wc * 64 + n * 16 + l15) * 32 + l4 * 8];
#pragma unroll
        for (int m = 0; m < 2; ++m)
#pragma unroll
            for (int n = 0; n < 4; ++n)
                acc[m][n] = __builtin_amdgcn_mfma_f32_16x16x32_bf16(af[m], bfr[n], acc[m][n], 0, 0, 0);
        asm volatile("" ::: "memory");
        __builtin_amdgcn_s_barrier();
        if (k < 14) QK_STAGE(k + 2, cur);
    }
#undef QK_STAGE

#pragma unroll
    for (int m = 0; m < 2; ++m)
#pragma unroll
        for (int n = 0; n < 4; ++n) {
            int pcol = p0 + wc * 64 + n * 16 + l15;
#pragma unroll
            for (int r = 0; r < 4; ++r) {
                int orow = wr * 32 + m * 16 + l4 * 4 + r;
                outb[(size_t)orow * PP + pcol] = f2bf(acc[m][n][r] + bias[orow]);
            }
        }
}

// ---------------- bf16 96x96 spatial transpose (q,k only) ----------------
__global__ __launch_bounds__(256) void thw_b(
    const unsigned short* __restrict__ in, unsigned short* __restrict__ out)
{
    size_t m = blockIdx.x;
    const unsigned short* im = in + m * (size_t)PP;
    unsigned short* om = out + m * (size_t)PP;
    __shared__ unsigned short T[96][97];
    int t = threadIdx.x;
#pragma unroll
    for (int i = 0; i < 18; ++i) {
        int v = t + 256 * i;
        int r = v / 48, pp = v - r * 48;
        ushort2v u = *(const ushort2v*)(im + r * 96 + pp * 2);
        T[r][pp * 2] = u.x;
        T[r][pp * 2 + 1] = u.y;
    }
    __syncthreads();
#pragma unroll
    for (int i = 0; i < 18; ++i) {
        int v = t + 256 * i;
        int w = v / 48, hh = v - w * 48;
        ushort2v o = { T[hh * 2][w], T[hh * 2 + 1][w] };
        *(ushort2v*)(om + w * 96 + hh * 2) = o;
    }
}

// ---------------- scores + exp + row-partial-sums: grid (96, 2, g) ----------------
__global__ __launch_bounds__(256) void scores_kernel(
    const unsigned short* __restrict__ qT, const unsigned short* __restrict__ kT,
    const unsigned short* __restrict__ q, const unsigned short* __restrict__ k,
    unsigned short* __restrict__ attb, float* __restrict__ rsum0, float* __restrict__ rsum1)
{
    int s = blockIdx.x;
    int ori = blockIdx.y;
    size_t b = blockIdx.z;
    const unsigned short* qs = (ori ? q : qT) + b * (size_t)C8P;
    const unsigned short* ks = (ori ? k : kT) + b * (size_t)C8P;
    unsigned short* ab = attb + b * (size_t)ATTN;
    float* rs = (ori ? rsum1 : rsum0) + b * (size_t)PP;

    __shared__ float Qs[64][97];
    __shared__ float Ks[64][97];
    int t = threadIdx.x;
    for (int v = t; v < 64 * 12; v += 256) {
        int c = v / 12, gg = v - c * 12;
        size_t gi = (size_t)c * PP + (size_t)s * 96 + gg * 8;
        ushort8 uq = *(const ushort8*)(qs + gi);
        ushort8 uk = *(const ushort8*)(ks + gi);
#pragma unroll
        for (int kk = 0; kk < 8; ++kk) {
            Qs[c][gg * 8 + kk] = bf2f(uq[kk]);
            Ks[c][gg * 8 + kk] = bf2f(uk[kk]);
        }
    }
    __syncthreads();
    int tx = t & 15, ty = t >> 4;
    float acc[6][6] = {};
    for (int c = 0; c < 64; ++c) {
        float qf[6], kf[6];
#pragma unroll
        for (int i = 0; i < 6; ++i) { qf[i] = Qs[c][ty + 16 * i]; kf[i] = Ks[c][tx + 16 * i]; }
#pragma unroll
        for (int i = 0; i < 6; ++i)
#pragma unroll
            for (int j = 0; j < 6; ++j) acc[i][j] = fmaf(qf[i], kf[j], acc[i][j]);
    }
#pragma unroll
    for (int i = 0; i < 6; ++i) {
        int m = ty + 16 * i;
        size_t row = ori ? ((size_t)s * 96 + m) : ((size_t)m * 96 + s);
        unsigned short* rowp = ab + row * 192 + (ori ? 96 : 0);
        float part = 0.0f;
#pragma unroll
        for (int j = 0; j < 6; ++j) {
            int jj = tx + 16 * j;
            float e = (!ori && jj == m) ? 0.0f : __expf(acc[i][j] - 20.0f);
            part += e;
            rowp[jj] = f2bf(e);
        }
#pragma unroll
        for (int off = 1; off < 16; off <<= 1) part += __shfl_xor(part, off);
        if (tx == 0) rs[row] = part;
    }
}

// ---------------- MFMA apply on x: yT[p][c] unnormalized (norm folded into gemm_out) ----------------
// grid (96 s, 4 = path*2+ct, g), 512 thr = 8 waves (2 m x 4 n)
// ORI=1 prefetches Y RMW operands before the MFMA phase (latency hidden under compute).
template<int ORI>
__global__ __launch_bounds__(512) void apply_mfma(
    const unsigned short* __restrict__ xT_e, const unsigned short* __restrict__ xT_q,
    unsigned short* __restrict__ yT_e, unsigned short* __restrict__ yT_q,
    const unsigned short* __restrict__ attb)
{
    int s = blockIdx.x;
    int path = blockIdx.y >> 1, ct = blockIdx.y & 1;
    int c0 = ct * 256;
    size_t b = blockIdx.z;
    const unsigned short* X = (path ? xT_q : xT_e) + b * (size_t)CP;
    unsigned short* Y = (path ? yT_q : yT_e) + b * (size_t)CP;
    const unsigned short* ab = attb + b * (size_t)ATTN;

    __shared__ __align__(16) unsigned short Att[96][104];
    __shared__ __align__(16) unsigned short Xs[256][104];   // [c][j] swizzled; reused as Wf[96][268]

    int tid = threadIdx.x;
    for (int v = tid; v < 96 * 12; v += 512) {
        int r = v / 12, gg = v - r * 12;
        size_t base = ORI ? ((size_t)(s * 96 + r) * 192 + 96) : ((size_t)(r * 96 + s) * 192);
        *(ushort8*)&Att[r][gg * 8] = *(const ushort8*)(ab + base + gg * 8);
    }
    // quad-j staging: 768 chunks (24 j-quads x 32 c-groups)
#pragma unroll
    for (int i = 0; i < 2; ++i) {
        int id = tid + 512 * i;
        if (id < 768) {
            int jq = id >> 5, cc = id & 31;
            int j = jq * 4;
            size_t stepP = ORI ? 1 : 96;
            size_t pj = ORI ? ((size_t)s * 96 + j) : ((size_t)j * 96 + s);
            const unsigned short* xp = X + pj * C_ + c0 + cc * 8;
            ushort8 u0 = *(const ushort8*)(xp);
            ushort8 u1 = *(const ushort8*)(xp + stepP * C_);
            ushort8 u2 = *(const ushort8*)(xp + 2 * stepP * C_);
            ushort8 u3 = *(const ushort8*)(xp + 3 * stepP * C_);
            int js = j ^ ((cc & 3) << 3);
#pragma unroll
            for (int e = 0; e < 8; ++e) {
                ushort4v o = { u0[e], u1[e], u2[e], u3[e] };
                *(ushort4v*)&Xs[cc * 8 + e][js] = o;
            }
        }
    }

    // ORI=1: prefetch Y RMW operands now; latency hides under the MFMA phase
    ushort8 yo[6];
    if (ORI) {
#pragma unroll
        for (int i = 0; i < 6; ++i) {
            int id = tid + 512 * i;
            int row = id >> 5, cg = id & 31;
            size_t p = (size_t)s * 96 + row;
            yo[i] = *(const ushort8*)(Y + p * C_ + c0 + cg * 8);
        }
    }
    __syncthreads();

    int lane = tid & 63, wid = tid >> 6;
    int wm = wid >> 2, wn = wid & 3;
    int l15 = lane & 15, l4 = lane >> 4;
    f32x4 acc[3][4] = {};
#pragma unroll
    for (int k = 0; k < 3; ++k) {
        bf16x8 a[3], xx[4];
#pragma unroll
        for (int mi = 0; mi < 3; ++mi)
            a[mi] = *(const bf16x8*)&Att[wm * 48 + mi * 16 + l15][k * 32 + l4 * 8];
#pragma unroll
        for (int ni = 0; ni < 4; ++ni) {
            int row = wn * 64 + ni * 16 + l15;
            int gsw = (k * 4 + l4) ^ ((row >> 3) & 3);
            xx[ni] = *(const bf16x8*)&Xs[row][gsw * 8];
        }
#pragma unroll
        for (int mi = 0; mi < 3; ++mi)
#pragma unroll
            for (int ni = 0; ni < 4; ++ni)
                acc[mi][ni] = __builtin_amdgcn_mfma_f32_16x16x32_bf16(a[mi], xx[ni], acc[mi][ni], 0, 0, 0);
    }

    // ---- repack epilogue (coalesced ushort8 stores / RMW adds) ----
    unsigned short* Wf = &Xs[0][0];     // row stride 268 u16 (bank-clean)
    __syncthreads();                    // all Xs reads complete before overwrite
#pragma unroll
    for (int mi = 0; mi < 3; ++mi)
#pragma unroll
        for (int r = 0; r < 4; ++r) {
            int mrow = wm * 48 + mi * 16 + l4 * 4 + r;
#pragma unroll
            for (int ni = 0; ni < 4; ++ni)
                Wf[mrow * 268 + wn * 64 + ni * 16 + l15] = f2bf(acc[mi][ni][r]);
        }
    __syncthreads();
#pragma unroll
    for (int i = 0; i < 6; ++i) {
        int id = tid + 512 * i;
        int row = id >> 5, cg = id & 31;
        ushort4v w0 = *(const ushort4v*)&Wf[row * 268 + cg * 8];
        ushort4v w1 = *(const ushort4v*)&Wf[row * 268 + cg * 8 + 4];
        size_t p = ORI ? ((size_t)s * 96 + row) : ((size_t)row * 96 + s);
        unsigned short* yp = Y + p * C_ + c0 + cg * 8;
        if (ORI == 0) {
            ushort8 o = { w0[0], w0[1], w0[2], w0[3], w1[0], w1[1], w1[2], w1[3] };
            *(ushort8*)yp = o;
        } else {
            ushort8 o;
#pragma unroll
            for (int e = 0; e < 4; ++e) o[e] = f2bf(bf2f(yo[i][e]) + bf2f(w0[e]));
#pragma unroll
            for (int e = 0; e < 4; ++e) o[e + 4] = f2bf(bf2f(yo[i][e + 4]) + bf2f(w1[e]));
            *(ushort8*)yp = o;
        }
    }
}

// ---------------- final GEMM + fused epilogue: 512 thr, BK=64, swizzle, counted-vmcnt dbuf,
//                  x-prefetch in K-loop, XCD-bijective remap, rinv loaded in prologue ----------------
__global__ __launch_bounds__(512) void gemm_out(
    const unsigned short* __restrict__ Wvb, const unsigned short* __restrict__ Wqvb,
    const unsigned short* __restrict__ yT_e, const unsigned short* __restrict__ yT_q,
    const float* __restrict__ bv, const float* __restrict__ bqv,
    const float* __restrict__ xe, const float* __restrict__ xq,
    const float* __restrict__ g1, const float* __restrict__ g2,
    const float* __restrict__ rsum0, const float* __restrict__ rsum1,
    float* __restrict__ o0, float* __restrict__ o1)
{
    // bijective XCD remap: 576 blocks/z; ot varies fastest within an XCD chunk
    int lin = blockIdx.x + 72 * blockIdx.y;
    int nid = (lin & 7) * 72 + (lin >> 3);
    int path = nid / 288;
    int rem = nid - path * 288;
    int ptile = rem >> 2, ot = rem & 3;

    const unsigned short* A = path ? Wqvb : Wvb;
    const float* bias = path ? bqv : bv;
    int p0 = ptile * 128;
    int o0r = ot * 128;
    size_t b = blockIdx.z;
    const unsigned short* Bb = (path ? yT_q : yT_e) + b * (size_t)CP;
    const float* xb = (path ? xq : xe) + b * (size_t)CP;
    float* ob = (path ? o1 : o0) + b * (size_t)CP;
    float gam = (path ? g2 : g1)[0];

    __shared__ __align__(16) unsigned short Asm[2][128 * 64];
    __shared__ __align__(16) unsigned short Bsm[2][128 * 64];

    int tid = threadIdx.x;             // 0..511, 8 waves
    int lane = tid & 63, wid = tid >> 6;
    int wr = wid >> 2, wc = wid & 3;   // 2 x 4 wave grid; wave tile 64 rows x 32 cols
    int l15 = lane & 15, l4 = lane >> 4;
    f32x4 acc[4][2] = {};
    float xv[4][2][4];                 // prefetched x residual (static-indexed)

#define GO_STAGE(KT, BUF)                                                                  \
    {                                                                                      \
        int k0s = (KT) * 64;                                                               \
        _Pragma("unroll")                                                                  \
        for (int i = 0; i < 2; ++i) {                                                      \
            int ch = tid + i * 512;                                                        \
            int row = ch >> 3, slot = ch & 7;                                              \
            int gs = slot ^ (row & 7);                                                     \
            gload16(A + (size_t)(o0r + row) * 512 + k0s + gs * 8, Asm[BUF] + ch * 8);      \
            gload16(Bb + (size_t)(p0 + row) * 512 + k0s + gs * 8, Bsm[BUF] + ch * 8);      \
        }                                                                                  \
    }

    GO_STAGE(0, 0);
    GO_STAGE(1, 1);

    // rinv operand loads issued in prologue; consumed only after final vmcnt(0).
    float rsa[2], rsb[2];
#pragma unroll
    for (int n = 0; n < 2; ++n) {
        int pcol = p0 + wc * 32 + n * 16 + l15;
        size_t pg = b * (size_t)PP + pcol;
        rsa[n] = rsum0[pg];
        rsb[n] = rsum1[pg];
    }

#pragma unroll
    for (int k = 0; k < 8; ++k) {
        int cur = k & 1;
        // queue at k==0: s0(4) oldest, then s1(4), rsum(4) => vmcnt(8) forces exactly s0.
        // steady k=1..6: s_k(4) oldest, then x_{k-1}(4), s_{k+1}(4) => vmcnt(8) forces s_k.
        // k==7: s7(4) oldest, x6(4) => vmcnt(4) forces s7.
        if (k == 0)      asm volatile("s_waitcnt vmcnt(8)" ::: "memory");
        else if (k < 7)  asm volatile("s_waitcnt vmcnt(8)" ::: "memory");
        else             asm volatile("s_waitcnt vmcnt(4)" ::: "memory");
        __builtin_amdgcn_s_barrier();
#pragma unroll
        for (int ks = 0; ks < 2; ++ks) {
            bf16x8 af[4], bfr[2];
#pragma unroll
            for (int m = 0; m < 4; ++m) {
                int row = wr * 64 + m * 16 + l15;
                int sl = (ks * 4 + l4) ^ (row & 7);
                af[m] = *(const bf16x8*)&Asm[cur][row * 64 + sl * 8];
            }
#pragma unroll
            for (int n = 0; n < 2; ++n) {
                int row = wc * 32 + n * 16 + l15;
                int sl = (ks * 4 + l4) ^ (row & 7);
                bfr[n] = *(const bf16x8*)&Bsm[cur][row * 64 + sl * 8];
            }
#pragma unroll
            for (int m = 0; m < 4; ++m)
#pragma unroll
                for (int n = 0; n < 2; ++n)
                    acc[m][n] = __builtin_amdgcn_mfma_f32_16x16x32_bf16(af[m], bfr[n], acc[m][n], 0, 0, 0);
        }
        asm volatile("" ::: "memory");
        __builtin_amdgcn_s_barrier();
        {   // x-prefetch chunk k: fragment (m = k>>1, n = k&1)
            int xm = k >> 1, xn = k & 1;
            int pcol = p0 + wc * 32 + xn * 16 + l15;
#pragma unroll
            for (int r = 0; r < 4; ++r) {
                int orow = o0r + wr * 64 + xm * 16 + l4 * 4 + r;
                xv[xm][xn][r] = xb[(size_t)orow * PP + pcol];
            }
        }
        if (k < 6) GO_STAGE(k + 2, cur);
    }
#undef GO_STAGE
    asm volatile("s_waitcnt vmcnt(0)" ::: "memory");

    float ri[2];
#pragma unroll
    for (int n = 0; n < 2; ++n) ri[n] = 1.0f / (rsa[n] + rsb[n]);

#pragma unroll
    for (int m = 0; m < 4; ++m)
#pragma unroll
        for (int n = 0; n < 2; ++n) {
            int pcol = p0 + wc * 32 + n * 16 + l15;
#pragma unroll
            for (int r = 0; r < 4; ++r) {
                int orow = o0r + wr * 64 + m * 16 + l4 * 4 + r;
                size_t idx = (size_t)orow * PP + pcol;
                float val = acc[m][n][r] * ri[n] + bias[orow];
                ob[idx] = gam * (val + 2.0f) + xv[m][n][r];
            }
        }
}

extern "C" void kernel_launch(void* const* d_in, const int* in_sizes, int n_in,
                              void* d_out, int out_size, void* d_ws, size_t ws_size,
                              hipStream_t stream)
{
    const float* x_ex = (const float*)d_in[0];
    const float* x_q  = (const float*)d_in[1];
    const float* Wq   = (const float*)d_in[2];
    const float* bq   = (const float*)d_in[3];
    const float* Wk   = (const float*)d_in[4];
    const float* bk   = (const float*)d_in[5];
    const float* Wv   = (const float*)d_in[6];
    const float* bv   = (const float*)d_in[7];
    const float* Wqv  = (const float*)d_in[8];
    const float* bqv  = (const float*)d_in[9];
    const float* g1   = (const float*)d_in[10];
    const float* g2   = (const float*)d_in[11];
    float* out0 = (float*)d_out;
    float* out1 = out0 + (size_t)8 * CP;

    unsigned short* hp = (unsigned short*)d_ws;
    unsigned short* Wvb  = hp; hp += 262144;
    unsigned short* Wqvb = hp; hp += 262144;
    unsigned short* Wqb  = hp; hp += 32768;
    unsigned short* Wkb  = hp; hp += 32768;
    size_t head = (size_t)(hp - (unsigned short*)d_ws) * 2;

    size_t perB = 4ull * CP + (size_t)ATTN + 4ull * C8P + 4ull * PP;
    int g = 8;
    while (g > 1 && head + (size_t)g * perB * 2 > ws_size) g >>= 1;

    unsigned short* p = hp;
    unsigned short* xT_e = p; p += (size_t)g * CP;
    unsigned short* xT_q = p; p += (size_t)g * CP;
    unsigned short* yT_e = p; p += (size_t)g * CP;
    unsigned short* yT_q = p; p += (size_t)g * CP;
    unsigned short* attb = p; p += (size_t)g * ATTN;
    unsigned short* qb   = p; p += (size_t)g * C8P;
    unsigned short* kb   = p; p += (size_t)g * C8P;  // adjacent to qb
    unsigned short* qTb  = p; p += (size_t)g * C8P;
    unsigned short* kTb  = p; p += (size_t)g * C8P;  // adjacent to qTb
    float* rsum0 = (float*)p; p += (size_t)g * PP * 2;
    float* rsum1 = (float*)p; p += (size_t)g * PP * 2;

    cast_w<<<dim3(256, 4), 256, 0, stream>>>(Wv, Wqv, Wq, Wk, Wvb, Wqvb, Wqb, Wkb);

    for (int b0 = 0; b0 < 8; b0 += g) {
        const float* xe = x_ex + (size_t)b0 * CP;
        const float* xq = x_q  + (size_t)b0 * CP;
        float* o0 = out0 + (size_t)b0 * CP;
        float* o1 = out1 + (size_t)b0 * CP;

        cast_transpose_cp<<<dim3(144, 8, 2 * g), 256, 0, stream>>>(xq, xe, xT_q, xT_e);
        gemm_qk<<<dim3(72, 2, g), 256, 0, stream>>>(Wqb, Wkb, xT_q, xT_e, bq, bk, qb, kb);
        thw_b<<<dim3(2 * g * 64), 256, 0, stream>>>(qb, qTb);
        scores_kernel<<<dim3(96, 2, g), 256, 0, stream>>>(qTb, kTb, qb, kb, attb, rsum0, rsum1);
        apply_mfma<0><<<dim3(96, 4, g), 512, 0, stream>>>(xT_e, xT_q, yT_e, yT_q, attb);
        apply_mfma<1><<<dim3(96, 4, g), 512, 0, stream>>>(xT_e, xT_q, yT_e, yT_q, attb);
        gemm_out<<<dim3(72, 8, g), 512, 0, stream>>>(Wvb, Wqvb, yT_e, yT_q, bv, bqv,
                                                     xe, xq, g1, g2, rsum0, rsum1, o0, o1);
    }
}